// Round 5
// baseline (8143.667 us; speedup 1.0000x reference)
//
#include <hip/hip_runtime.h>
#include <hip/hip_bf16.h>
#include <math.h>

#define BB 64
#define HW 196
#define FEAT 2048
#define EMB 512
#define HID 1024
#define ATT 512
#define VOCAB 10000
#define TT 20
#define STEPS 19

#define G_BLOCKS 256
#define G_THREADS 1024
#define NGRP 16
#define GRPSZ 16

using bfrag = __attribute__((ext_vector_type(8))) short;   // 8 bf16 = 4 VGPR
using f32x4 = __attribute__((ext_vector_type(4))) float;

__device__ __forceinline__ float sigmoid_fast(float x) { return 1.0f / (1.0f + __expf(-x)); }
__device__ __forceinline__ float tanh_fast(float x) {
    float e = __expf(2.0f * x);
    return 1.0f - 2.0f / (e + 1.0f);
}
__device__ __forceinline__ ushort f2bf_rne(float f) {
    unsigned u = __float_as_uint(f);
    unsigned r = (u + 0x7FFFu + ((u >> 16) & 1u)) >> 16;
    return (ushort)r;
}
__device__ __forceinline__ float bf2f(ushort h) {
    return __uint_as_float(((unsigned)h) << 16);
}

// ---------------------------------------------------------------------------
// fp32 -> split bf16 planes: x = hi + lo.  n % 1024 == 0.
// ---------------------------------------------------------------------------
__global__ __launch_bounds__(256) void k_split(const float* __restrict__ x,
                                               ushort* __restrict__ hi,
                                               ushort* __restrict__ lo, int n)
{
    int i4 = (blockIdx.x * 256 + threadIdx.x) * 4;
    if (i4 >= n) return;
    float4 v = *(const float4*)(x + i4);
    float av[4] = {v.x, v.y, v.z, v.w};
    #pragma unroll
    for (int j = 0; j < 4; ++j) {
        ushort h = f2bf_rne(av[j]);
        hi[i4 + j] = h;
        lo[i4 + j] = f2bf_rne(av[j] - bf2f(h));
    }
}

// ---------------------------------------------------------------------------
// MFMA split-bf16 NT GEMM: C = A.B^T + bias, 3-term (Ah*Bh + Ah*Bl + Al*Bh).
// Tile 64(M) x NU*64(N), BK=32, 4 waves; wave w owns cols [w*NU*16, +NU*16).
// C/D layout (m89-verified): col = lane&15, row = (lane>>4)*4 + reg.
// ---------------------------------------------------------------------------
template<int NU>
__global__ __launch_bounds__(256) void mfma_nt(
    const float* __restrict__ A,
    const ushort* __restrict__ Bhi, const ushort* __restrict__ Blo,
    const float* __restrict__ bias, float* __restrict__ C,
    int Mvalid, int N, int K, int ldc)
{
    __shared__ __align__(16) ushort sAh[4][64][8];
    __shared__ __align__(16) ushort sAl[4][64][8];
    __shared__ __align__(16) ushort sBh[4][NU * 64][8];
    __shared__ __align__(16) ushort sBl[4][NU * 64][8];

    const int tid = threadIdx.x;
    const int m0 = blockIdx.y * 64;
    const int n0 = blockIdx.x * (NU * 64);

    const int ag = tid >> 6, ar = tid & 63;
    const float* aptr = A + (size_t)(m0 + ar) * K + ag * 8;
    const int nr = min(n0 + tid, N - 1);
    const ushort* bhp = Bhi + (size_t)nr * K;
    const ushort* blp = Blo + (size_t)nr * K;

    const int lane = tid & 63;
    const int w = tid >> 6;
    const int g = lane >> 4, l15 = lane & 15;

    f32x4 acc[4][NU] = {};

    for (int k0 = 0; k0 < K; k0 += 32) {
        __syncthreads();
        {
            float av[8];
            *(float4*)(av)     = *(const float4*)(aptr + k0);
            *(float4*)(av + 4) = *(const float4*)(aptr + k0 + 4);
            bfrag vh, vl;
            #pragma unroll
            for (int j = 0; j < 8; ++j) {
                ushort h = f2bf_rne(av[j]);
                vh[j] = (short)h;
                vl[j] = (short)f2bf_rne(av[j] - bf2f(h));
            }
            *(bfrag*)&sAh[ag][ar][0] = vh;
            *(bfrag*)&sAl[ag][ar][0] = vl;
        }
        if (tid < NU * 64) {
            #pragma unroll
            for (int q = 0; q < 4; ++q) {
                *(bfrag*)&sBh[q][tid][0] = *(const bfrag*)(bhp + k0 + q * 8);
                *(bfrag*)&sBl[q][tid][0] = *(const bfrag*)(blp + k0 + q * 8);
            }
        }
        __syncthreads();

        bfrag ah[4], al[4], bh[NU], bl[NU];
        #pragma unroll
        for (int s = 0; s < 4; ++s) {
            ah[s] = *(const bfrag*)&sAh[g][s * 16 + l15][0];
            al[s] = *(const bfrag*)&sAl[g][s * 16 + l15][0];
        }
        #pragma unroll
        for (int u = 0; u < NU; ++u) {
            bh[u] = *(const bfrag*)&sBh[g][w * NU * 16 + u * 16 + l15][0];
            bl[u] = *(const bfrag*)&sBl[g][w * NU * 16 + u * 16 + l15][0];
        }
        #pragma unroll
        for (int s = 0; s < 4; ++s)
            #pragma unroll
            for (int u = 0; u < NU; ++u) {
                acc[s][u] = __builtin_amdgcn_mfma_f32_16x16x32_bf16(ah[s], bh[u], acc[s][u], 0, 0, 0);
                acc[s][u] = __builtin_amdgcn_mfma_f32_16x16x32_bf16(ah[s], bl[u], acc[s][u], 0, 0, 0);
                acc[s][u] = __builtin_amdgcn_mfma_f32_16x16x32_bf16(al[s], bh[u], acc[s][u], 0, 0, 0);
            }
    }

    #pragma unroll
    for (int s = 0; s < 4; ++s)
        #pragma unroll
        for (int u = 0; u < NU; ++u) {
            int col = n0 + w * NU * 16 + u * 16 + l15;
            if (col < N) {
                float bv = bias[col];
                #pragma unroll
                for (int r = 0; r < 4; ++r) {
                    int row = m0 + s * 16 + g * 4 + r;
                    if (row < Mvalid)
                        C[(size_t)row * ldc + col] = acc[s][u][r] + bv;
                }
            }
        }
}

// ---------------------------------------------------------------------------
__global__ __launch_bounds__(256) void k_fmean(const float* __restrict__ f,
                                               float* __restrict__ fmean)
{
    int b = blockIdx.x, tid = threadIdx.x;
    for (int e = tid; e < EMB; e += 256) {
        const float* fb = f + (size_t)b * HW * EMB + e;
        float s = 0.f;
        for (int h = 0; h < HW; ++h) s += fb[(size_t)h * EMB];
        fmean[b * EMB + e] = s * (1.0f / HW);
    }
}

__global__ __launch_bounds__(256) void k_init(
    const float* __restrict__ fmean,
    const float* __restrict__ W_hi, const float* __restrict__ b_hi,
    const float* __restrict__ W_ci, const float* __restrict__ b_ci,
    float* __restrict__ hx, float* __restrict__ cx)
{
    int b = blockIdx.x, tid = threadIdx.x;
    __shared__ float fm[EMB];
    for (int i = tid; i < EMB; i += 256) fm[i] = fmean[b * EMB + i];
    __syncthreads();
    for (int u = tid; u < HID; u += 256) {
        const float4* w1 = (const float4*)(W_hi + (size_t)u * EMB);
        const float4* w2 = (const float4*)(W_ci + (size_t)u * EMB);
        float a1 = b_hi[u], a2 = b_ci[u];
        for (int k = 0; k < EMB / 4; ++k) {
            float4 y1 = w1[k], y2 = w2[k];
            float x0 = fm[4*k], x1 = fm[4*k+1], x2 = fm[4*k+2], x3 = fm[4*k+3];
            a1 += x0*y1.x + x1*y1.y + x2*y1.z + x3*y1.w;
            a2 += x0*y2.x + x1*y2.y + x2*y2.z + x3*y2.w;
        }
        hx[b * HID + u] = a1;
        cx[b * HID + u] = a2;
    }
}

// xs_hi/lo[t*64+b][:] = split(E[captions[b][t]][:])
__global__ __launch_bounds__(128) void k_embed_split(
    const int* __restrict__ cap, const float* __restrict__ E,
    ushort* __restrict__ xs_hi, ushort* __restrict__ xs_lo)
{
    int blk = blockIdx.x;
    int t = blk / BB, b = blk % BB;
    int c = cap[b * TT + t];
    float4 v = ((const float4*)(E + (size_t)c * EMB))[threadIdx.x];
    float av[4] = {v.x, v.y, v.z, v.w};
    ushort h[4], l[4];
    #pragma unroll
    for (int j = 0; j < 4; ++j) {
        h[j] = f2bf_rne(av[j]);
        l[j] = f2bf_rne(av[j] - bf2f(h[j]));
    }
    size_t base = ((size_t)t * BB + b) * EMB + threadIdx.x * 4;
    *(ushort4*)(xs_hi + base) = make_ushort4(h[0], h[1], h[2], h[3]);
    *(ushort4*)(xs_lo + base) = make_ushort4(l[0], l[1], l[2], l[3]);
}

__global__ void k_bar_init(int* bar) { bar[threadIdx.x] = 0; }

// ---------------------------------------------------------------------------
// Hierarchical grid barrier: 16 groups x 16 blocks on separate cache lines,
// then 16 root adds. Agent-scope (cross-XCD safe). Sense-reversal via gen.
// ---------------------------------------------------------------------------
__device__ __forceinline__ void gbar(int* bar) {
    __syncthreads();
    if (threadIdx.x == 0) {
        __threadfence();
        int* gen  = bar;
        int* rcnt = bar + 32;
        int* gcnt = bar + 64 + (blockIdx.x & (NGRP - 1)) * 32;
        int g = __hip_atomic_load(gen, __ATOMIC_RELAXED, __HIP_MEMORY_SCOPE_AGENT);
        bool root_done = false;
        if (__hip_atomic_fetch_add(gcnt, 1, __ATOMIC_ACQ_REL, __HIP_MEMORY_SCOPE_AGENT)
            == GRPSZ - 1) {
            __hip_atomic_store(gcnt, 0, __ATOMIC_RELAXED, __HIP_MEMORY_SCOPE_AGENT);
            if (__hip_atomic_fetch_add(rcnt, 1, __ATOMIC_ACQ_REL, __HIP_MEMORY_SCOPE_AGENT)
                == NGRP - 1) {
                __hip_atomic_store(rcnt, 0, __ATOMIC_RELAXED, __HIP_MEMORY_SCOPE_AGENT);
                __hip_atomic_fetch_add(gen, 1, __ATOMIC_RELEASE, __HIP_MEMORY_SCOPE_AGENT);
                root_done = true;
            }
        }
        if (!root_done) {
            while (__hip_atomic_load(gen, __ATOMIC_ACQUIRE, __HIP_MEMORY_SCOPE_AGENT) == g)
                __builtin_amdgcn_s_sleep(1);
        }
    }
    __syncthreads();
}

// ---------------------------------------------------------------------------
// Persistent step loop. 256 blocks x 1024 threads (16 waves), 1 block/CU.
// Per step: phase1 (attention, blocks 0..63, block-local) -> gbar ->
//           phase2 (gates MFMA + fused LSTM, all 256 blocks) -> gbar.
// hx bf16 planes double-buffered by step parity (cross-block WAR safety).
// ---------------------------------------------------------------------------
__global__ __launch_bounds__(G_THREADS, 4) void k_steps(
    const ushort* __restrict__ xs_hi, const ushort* __restrict__ xs_lo,
    const float* __restrict__ f, const float* __restrict__ fa,
    const float* __restrict__ W2, const float* __restrict__ b2,
    const float* __restrict__ V,
    const ushort* __restrict__ wih_hi, const ushort* __restrict__ wih_lo,
    const ushort* __restrict__ whh_hi, const ushort* __restrict__ whh_lo,
    const float* __restrict__ b_ih, const float* __restrict__ b_hh,
    ushort* __restrict__ ctx_hi, ushort* __restrict__ ctx_lo,
    ushort* __restrict__ hxbf,            // [2 bufs][hi|lo][65536]
    float* __restrict__ hx, float* __restrict__ cx,
    float* __restrict__ hx_all, int* __restrict__ bar)
{
    __shared__ __align__(16) float smem[4096];   // 16 KB, phase-aliased
    const int tid = threadIdx.x;
    const int blk = blockIdx.x;
    const int lane = tid & 63;
    const int wid = tid >> 6;
    const int l15 = lane & 15;

    for (int t = 0; t < STEPS; ++t) {
        // ================= Phase 1: attention (blocks 0..63) =================
        if (blk < BB) {
            const int b = blk;
            float* hx_s = smem;          // 1024
            float* ha_s = smem + 1024;   // 512
            float* V_s  = smem + 1536;   // 512
            float* w_s  = smem + 2048;   // 256 (196 used)
            float* red  = smem + 2304;   // 256
            float* pc   = smem + 2560;   // 512

            hx_s[tid] = hx[b * HID + tid];
            if (tid < ATT) V_s[tid] = V[tid];
            __syncthreads();

            // ha[a] = hx . W2[a] + b2[a]
            for (int a = wid; a < ATT; a += 16) {
                const float4* wr = (const float4*)(W2 + (size_t)a * HID);
                float s = 0.f;
                #pragma unroll
                for (int q = 0; q < 4; ++q) {
                    int i4 = q * 64 + lane;
                    float4 w = wr[i4];
                    float4 x = *(const float4*)&hx_s[i4 * 4];
                    s += w.x*x.x + w.y*x.y + w.z*x.z + w.w*x.w;
                }
                #pragma unroll
                for (int off = 32; off > 0; off >>= 1) s += __shfl_down(s, off);
                if (lane == 0) ha_s[a] = s + b2[a];
            }
            __syncthreads();

            // logits[h] (bV omitted: softmax-invariant)
            for (int h = wid; h < HW; h += 16) {
                const float4* fr = (const float4*)(fa + ((size_t)b * HW + h) * ATT);
                float s = 0.f;
                #pragma unroll
                for (int q = 0; q < 2; ++q) {
                    int i4 = q * 64 + lane;
                    float4 fv = fr[i4];
                    float4 hv = *(const float4*)&ha_s[i4 * 4];
                    float4 vv = *(const float4*)&V_s[i4 * 4];
                    s += tanh_fast(fv.x + hv.x) * vv.x + tanh_fast(fv.y + hv.y) * vv.y
                       + tanh_fast(fv.z + hv.z) * vv.z + tanh_fast(fv.w + hv.w) * vv.w;
                }
                #pragma unroll
                for (int off = 32; off > 0; off >>= 1) s += __shfl_down(s, off);
                if (lane == 0) w_s[h] = s;
            }
            __syncthreads();

            // softmax over 196
            float v = (tid < HW) ? w_s[tid] : -INFINITY;
            if (tid < 256) red[tid] = v;
            __syncthreads();
            for (int s2 = 128; s2 > 0; s2 >>= 1) {
                if (tid < s2) red[tid] = fmaxf(red[tid], red[tid + s2]);
                __syncthreads();
            }
            float mx = red[0];
            __syncthreads();
            float e = (tid < HW) ? __expf(v - mx) : 0.f;
            if (tid < 256) red[tid] = e;
            __syncthreads();
            for (int s2 = 128; s2 > 0; s2 >>= 1) {
                if (tid < s2) red[tid] += red[tid + s2];
                __syncthreads();
            }
            float inv = 1.0f / red[0];
            if (tid < HW) w_s[tid] = e * inv;
            __syncthreads();

            // ctx[e] = sum_h w[h] * f[b][h][e]; write split-bf16
            {
                int e0 = tid & 511, grp = tid >> 9;
                const float* fb = f + (size_t)b * HW * EMB + e0;
                float s = 0.f;
                for (int h = grp; h < HW; h += 2)
                    s = fmaf(w_s[h], fb[(size_t)h * EMB], s);
                if (grp) pc[e0] = s;
                __syncthreads();
                if (!grp) {
                    float c = s + pc[e0];
                    ushort ch = f2bf_rne(c);
                    ctx_hi[b * EMB + e0] = ch;
                    ctx_lo[b * EMB + e0] = f2bf_rne(c - bf2f(ch));
                }
            }
        }
        gbar(bar);

        // ====== Phase 2: gates MFMA (3-term split-bf16) + fused LSTM ======
        {
            const int ms = wid & 3, ks = wid >> 2;
            const int arow = ms * 16 + l15;                  // batch row
            const int gate = l15 >> 2, uu = l15 & 3;
            const int ncol = gate * 1024 + blk * 4 + uu;     // weight row
            const int g8 = (lane >> 4) * 8;

            const ushort* hxr = hxbf + (size_t)(t & 1) * 131072;
            const ushort *ahp, *alp, *whp, *wlp;
            if (ks == 0) {
                size_t ab = ((size_t)t * BB + arow) * 512 + g8;
                ahp = xs_hi + ab; alp = xs_lo + ab;
                size_t wb = (size_t)ncol * 1024 + g8;
                whp = wih_hi + wb; wlp = wih_lo + wb;
            } else if (ks == 1) {
                size_t ab = (size_t)arow * 512 + g8;
                ahp = ctx_hi + ab; alp = ctx_lo + ab;
                size_t wb = (size_t)ncol * 1024 + 512 + g8;
                whp = wih_hi + wb; wlp = wih_lo + wb;
            } else if (ks == 2) {
                size_t ab = (size_t)arow * 1024 + g8;
                ahp = hxr + ab; alp = hxr + 65536 + ab;
                size_t wb = (size_t)ncol * 1024 + g8;
                whp = whh_hi + wb; wlp = whh_lo + wb;
            } else {
                size_t ab = (size_t)arow * 1024 + 512 + g8;
                ahp = hxr + ab; alp = hxr + 65536 + ab;
                size_t wb = (size_t)ncol * 1024 + 512 + g8;
                whp = whh_hi + wb; wlp = whh_lo + wb;
            }

            f32x4 acc = {};
            #pragma unroll 4
            for (int kk = 0; kk < 16; ++kk) {
                bfrag a_h = *(const bfrag*)(ahp + kk * 32);
                bfrag a_l = *(const bfrag*)(alp + kk * 32);
                bfrag b_h = *(const bfrag*)(whp + kk * 32);
                bfrag b_l = *(const bfrag*)(wlp + kk * 32);
                acc = __builtin_amdgcn_mfma_f32_16x16x32_bf16(a_h, b_h, acc, 0, 0, 0);
                acc = __builtin_amdgcn_mfma_f32_16x16x32_bf16(a_h, b_l, acc, 0, 0, 0);
                acc = __builtin_amdgcn_mfma_f32_16x16x32_bf16(a_l, b_h, acc, 0, 0, 0);
            }
            __syncthreads();   // smem free (phase1 done block-locally)
            #pragma unroll
            for (int r = 0; r < 4; ++r)
                smem[ks * 1024 + ms * 256 + ((lane >> 4) * 4 + r) * 16 + l15] = acc[r];
            __syncthreads();

            if (tid < 256) {
                int b = tid >> 2, u4 = tid & 3;
                int u = blk * 4 + u4;
                int base = (b >> 4) * 256 + (b & 15) * 16 + u4;
                float gs[4];
                #pragma unroll
                for (int gt = 0; gt < 4; ++gt) {
                    float s = 0.f;
                    #pragma unroll
                    for (int kq = 0; kq < 4; ++kq) s += smem[kq * 1024 + base + gt * 4];
                    gs[gt] = s;
                }
                float gi = gs[0] + b_ih[u]        + b_hh[u];
                float gf = gs[1] + b_ih[1024 + u] + b_hh[1024 + u];
                float gg = gs[2] + b_ih[2048 + u] + b_hh[2048 + u];
                float go = gs[3] + b_ih[3072 + u] + b_hh[3072 + u];
                int idx = b * 1024 + u;
                float c = sigmoid_fast(gf) * cx[idx] + sigmoid_fast(gi) * tanh_fast(gg);
                float h = sigmoid_fast(go) * tanh_fast(c);
                cx[idx] = c;
                hx[idx] = h;
                hx_all[(size_t)t * BB * HID + idx] = h;
                ushort hh = f2bf_rne(h);
                ushort* hxw = hxbf + (size_t)((t + 1) & 1) * 131072;
                hxw[idx] = hh;
                hxw[65536 + idx] = f2bf_rne(h - bf2f(hh));
            }
        }
        if (t != STEPS - 1) gbar(bar);
    }
}

// ---------------------------------------------------------------------------
extern "C" void kernel_launch(void* const* d_in, const int* in_sizes, int n_in,
                              void* d_out, int out_size, void* d_ws, size_t ws_size,
                              hipStream_t stream) {
    const float* features = (const float*)d_in[0];
    const int*   captions = (const int*)d_in[1];
    const float* E      = (const float*)d_in[3];
    const float* W_feat = (const float*)d_in[4];
    const float* b_feat = (const float*)d_in[5];
    const float* W1     = (const float*)d_in[6];
    const float* b1     = (const float*)d_in[7];
    const float* W2     = (const float*)d_in[8];
    const float* b2     = (const float*)d_in[9];
    const float* V      = (const float*)d_in[10];
    // d_in[11] bV: softmax-invariant, unused
    const float* W_hi   = (const float*)d_in[12];
    const float* b_hi   = (const float*)d_in[13];
    const float* W_ci   = (const float*)d_in[14];
    const float* b_ci   = (const float*)d_in[15];
    const float* W_ih   = (const float*)d_in[16];
    const float* b_ih   = (const float*)d_in[17];
    const float* W_hh   = (const float*)d_in[18];
    const float* b_hh   = (const float*)d_in[19];
    const float* W_out  = (const float*)d_in[20];
    const float* b_out  = (const float*)d_in[21];
    float* out = (float*)d_out;

    // ---- workspace layout ----
    float* ws = (float*)d_ws;
    float* f_buf   = ws;                          // 6,422,528
    float* fa_buf  = f_buf + 6422528;             // 6,422,528
    float* fmean   = fa_buf + 6422528;            // 32,768
    float* hx      = fmean + 32768;               // 65,536
    float* cx      = hx + 65536;                  // 65,536
    float* hx_all  = cx + 65536;                  // 1,310,720
    int*   bar     = (int*)(hx_all + 1310720);    // 1024 ints
    ushort* p = (ushort*)(bar + 1024);
    ushort* wfeat_hi = p;            p += 1048576;
    ushort* wfeat_lo = p;            p += 1048576;
    ushort* w1_hi    = p;            p += 262144;
    ushort* w1_lo    = p;            p += 262144;
    ushort* wih_hi   = p;            p += 4194304;
    ushort* wih_lo   = p;            p += 4194304;
    ushort* whh_hi   = p;            p += 4194304;
    ushort* whh_lo   = p;            p += 4194304;
    ushort* xs_hi    = p;            p += 622592;
    ushort* xs_lo    = p;            p += 622592;
    ushort* ctx_hi   = p;            p += 32768;
    ushort* ctx_lo   = p;            p += 32768;
    ushort* hxbf     = p;            p += 262144;   // [2][hi|lo][65536]
    // W_out planes reuse f_buf/fa_buf region after k_steps
    ushort* wout_hi = (ushort*)f_buf;
    ushort* wout_lo = wout_hi + 10240000;

    // ---- precompute ----
    k_bar_init<<<1, 1024, 0, stream>>>(bar);
    k_split<<<1048576 / 4 / 256, 256, 0, stream>>>(W_feat, wfeat_hi, wfeat_lo, 1048576);
    k_split<<<262144 / 4 / 256, 256, 0, stream>>>(W1, w1_hi, w1_lo, 262144);
    k_split<<<4194304 / 4 / 256, 256, 0, stream>>>(W_ih, wih_hi, wih_lo, 4194304);
    k_split<<<4194304 / 4 / 256, 256, 0, stream>>>(W_hh, whh_hi, whh_lo, 4194304);
    // f = features @ W_feat^T + b_feat  [12544,512], K=2048
    mfma_nt<2><<<dim3(4, 196), 256, 0, stream>>>(
        features, wfeat_hi, wfeat_lo, b_feat, f_buf, 12544, 512, 2048, 512);
    // fa = f @ W1^T + b1  [12544,512], K=512
    mfma_nt<2><<<dim3(4, 196), 256, 0, stream>>>(
        f_buf, w1_hi, w1_lo, b1, fa_buf, 12544, 512, 512, 512);
    k_fmean<<<BB, 256, 0, stream>>>(f_buf, fmean);
    k_init<<<BB, 256, 0, stream>>>(fmean, W_hi, b_hi, W_ci, b_ci, hx, cx);
    k_split<<<65536 / 4 / 256, 256, 0, stream>>>(hx, hxbf, hxbf + 65536, 65536);
    k_embed_split<<<STEPS * BB, 128, 0, stream>>>(captions, E, xs_hi, xs_lo);

    // ---- all 19 steps in one persistent kernel ----
    k_steps<<<G_BLOCKS, G_THREADS, 0, stream>>>(
        xs_hi, xs_lo, f_buf, fa_buf, W2, b2, V,
        wih_hi, wih_lo, whh_hi, whh_lo, b_ih, b_hh,
        ctx_hi, ctx_lo, hxbf, hx, cx, hx_all, bar);

    // ---- vocab projection over all steps: [1216,10000], K=1024 ----
    k_split<<<10240000 / 4 / 256, 256, 0, stream>>>(W_out, wout_hi, wout_lo, 10240000);
    mfma_nt<4><<<dim3(40, 20), 256, 0, stream>>>(
        hx_all, wout_hi, wout_lo, b_out, out, STEPS * BB, VOCAB, HID, VOCAB);
}

// Round 6
// 4236.415 us; speedup vs baseline: 1.9223x; 1.9223x over previous
//
#include <hip/hip_runtime.h>
#include <hip/hip_bf16.h>
#include <math.h>

#define BB 64
#define HW 196
#define FEAT 2048
#define EMB 512
#define HID 1024
#define ATT 512
#define VOCAB 10000
#define TT 20
#define STEPS 19

using bfrag = __attribute__((ext_vector_type(8))) short;   // 8 bf16 = 4 VGPR
using f32x4 = __attribute__((ext_vector_type(4))) float;

__device__ __forceinline__ float sigmoid_fast(float x) { return 1.0f / (1.0f + __expf(-x)); }
__device__ __forceinline__ float tanh_fast(float x) {
    float e = __expf(2.0f * x);
    return 1.0f - 2.0f / (e + 1.0f);
}
__device__ __forceinline__ ushort f2bf_rne(float f) {
    unsigned u = __float_as_uint(f);
    unsigned r = (u + 0x7FFFu + ((u >> 16) & 1u)) >> 16;
    return (ushort)r;
}
__device__ __forceinline__ float bf2f(ushort h) {
    return __uint_as_float(((unsigned)h) << 16);
}

// ---------------------------------------------------------------------------
// fp32 -> split bf16 planes: x = hi + lo.  n % 1024 == 0.
// ---------------------------------------------------------------------------
__global__ __launch_bounds__(256) void k_split(const float* __restrict__ x,
                                               ushort* __restrict__ hi,
                                               ushort* __restrict__ lo, int n)
{
    int i4 = (blockIdx.x * 256 + threadIdx.x) * 4;
    if (i4 >= n) return;
    float4 v = *(const float4*)(x + i4);
    float av[4] = {v.x, v.y, v.z, v.w};
    #pragma unroll
    for (int j = 0; j < 4; ++j) {
        ushort h = f2bf_rne(av[j]);
        hi[i4 + j] = h;
        lo[i4 + j] = f2bf_rne(av[j] - bf2f(h));
    }
}

// ---------------------------------------------------------------------------
// MFMA split-bf16 NT GEMM: C = A.B^T + bias, 3-term (Ah*Bh + Ah*Bl + Al*Bh).
// Tile 64(M) x NU*64(N), BK=32, 4 waves; wave w owns cols [w*NU*16, +NU*16).
// C/D layout: col = lane&15, row = (lane>>4)*4 + reg.
// ---------------------------------------------------------------------------
template<int NU>
__global__ __launch_bounds__(256) void mfma_nt(
    const float* __restrict__ A,
    const ushort* __restrict__ Bhi, const ushort* __restrict__ Blo,
    const float* __restrict__ bias, float* __restrict__ C,
    int Mvalid, int N, int K, int ldc)
{
    __shared__ __align__(16) ushort sAh[4][64][8];
    __shared__ __align__(16) ushort sAl[4][64][8];
    __shared__ __align__(16) ushort sBh[4][NU * 64][8];
    __shared__ __align__(16) ushort sBl[4][NU * 64][8];

    const int tid = threadIdx.x;
    const int m0 = blockIdx.y * 64;
    const int n0 = blockIdx.x * (NU * 64);

    const int ag = tid >> 6, ar = tid & 63;
    const float* aptr = A + (size_t)(m0 + ar) * K + ag * 8;
    const int nr = min(n0 + tid, N - 1);
    const ushort* bhp = Bhi + (size_t)nr * K;
    const ushort* blp = Blo + (size_t)nr * K;

    const int lane = tid & 63;
    const int w = tid >> 6;
    const int g = lane >> 4, l15 = lane & 15;

    f32x4 acc[4][NU] = {};

    for (int k0 = 0; k0 < K; k0 += 32) {
        __syncthreads();
        {
            float av[8];
            *(float4*)(av)     = *(const float4*)(aptr + k0);
            *(float4*)(av + 4) = *(const float4*)(aptr + k0 + 4);
            bfrag vh, vl;
            #pragma unroll
            for (int j = 0; j < 8; ++j) {
                ushort h = f2bf_rne(av[j]);
                vh[j] = (short)h;
                vl[j] = (short)f2bf_rne(av[j] - bf2f(h));
            }
            *(bfrag*)&sAh[ag][ar][0] = vh;
            *(bfrag*)&sAl[ag][ar][0] = vl;
        }
        if (tid < NU * 64) {
            #pragma unroll
            for (int q = 0; q < 4; ++q) {
                *(bfrag*)&sBh[q][tid][0] = *(const bfrag*)(bhp + k0 + q * 8);
                *(bfrag*)&sBl[q][tid][0] = *(const bfrag*)(blp + k0 + q * 8);
            }
        }
        __syncthreads();

        bfrag ah[4], al[4], bh[NU], bl[NU];
        #pragma unroll
        for (int s = 0; s < 4; ++s) {
            ah[s] = *(const bfrag*)&sAh[g][s * 16 + l15][0];
            al[s] = *(const bfrag*)&sAl[g][s * 16 + l15][0];
        }
        #pragma unroll
        for (int u = 0; u < NU; ++u) {
            bh[u] = *(const bfrag*)&sBh[g][w * NU * 16 + u * 16 + l15][0];
            bl[u] = *(const bfrag*)&sBl[g][w * NU * 16 + u * 16 + l15][0];
        }
        #pragma unroll
        for (int s = 0; s < 4; ++s)
            #pragma unroll
            for (int u = 0; u < NU; ++u) {
                acc[s][u] = __builtin_amdgcn_mfma_f32_16x16x32_bf16(ah[s], bh[u], acc[s][u], 0, 0, 0);
                acc[s][u] = __builtin_amdgcn_mfma_f32_16x16x32_bf16(ah[s], bl[u], acc[s][u], 0, 0, 0);
                acc[s][u] = __builtin_amdgcn_mfma_f32_16x16x32_bf16(al[s], bh[u], acc[s][u], 0, 0, 0);
            }
    }

    #pragma unroll
    for (int s = 0; s < 4; ++s)
        #pragma unroll
        for (int u = 0; u < NU; ++u) {
            int col = n0 + w * NU * 16 + u * 16 + l15;
            if (col < N) {
                float bv = bias[col];
                #pragma unroll
                for (int r = 0; r < 4; ++r) {
                    int row = m0 + s * 16 + g * 4 + r;
                    if (row < Mvalid)
                        C[(size_t)row * ldc + col] = acc[s][u][r] + bv;
                }
            }
        }
}

// ---------------------------------------------------------------------------
__global__ __launch_bounds__(256) void k_fmean(const float* __restrict__ f,
                                               float* __restrict__ fmean)
{
    int b = blockIdx.x, tid = threadIdx.x;
    for (int e = tid; e < EMB; e += 256) {
        const float* fb = f + (size_t)b * HW * EMB + e;
        float s = 0.f;
        for (int h = 0; h < HW; ++h) s += fb[(size_t)h * EMB];
        fmean[b * EMB + e] = s * (1.0f / HW);
    }
}

__global__ __launch_bounds__(256) void k_init(
    const float* __restrict__ fmean,
    const float* __restrict__ W_hi, const float* __restrict__ b_hi,
    const float* __restrict__ W_ci, const float* __restrict__ b_ci,
    float* __restrict__ hx, float* __restrict__ cx)
{
    int b = blockIdx.x, tid = threadIdx.x;
    __shared__ float fm[EMB];
    for (int i = tid; i < EMB; i += 256) fm[i] = fmean[b * EMB + i];
    __syncthreads();
    for (int u = tid; u < HID; u += 256) {
        const float4* w1 = (const float4*)(W_hi + (size_t)u * EMB);
        const float4* w2 = (const float4*)(W_ci + (size_t)u * EMB);
        float a1 = b_hi[u], a2 = b_ci[u];
        for (int k = 0; k < EMB / 4; ++k) {
            float4 y1 = w1[k], y2 = w2[k];
            float x0 = fm[4*k], x1 = fm[4*k+1], x2 = fm[4*k+2], x3 = fm[4*k+3];
            a1 += x0*y1.x + x1*y1.y + x2*y1.z + x3*y1.w;
            a2 += x0*y2.x + x1*y2.y + x2*y2.z + x3*y2.w;
        }
        hx[b * HID + u] = a1;
        cx[b * HID + u] = a2;
    }
}

// xs_hi/lo[t*64+b][:] = split(E[captions[b][t]][:])
__global__ __launch_bounds__(128) void k_embed_split(
    const int* __restrict__ cap, const float* __restrict__ E,
    ushort* __restrict__ xs_hi, ushort* __restrict__ xs_lo)
{
    int blk = blockIdx.x;
    int t = blk / BB, b = blk % BB;
    int c = cap[b * TT + t];
    float4 v = ((const float4*)(E + (size_t)c * EMB))[threadIdx.x];
    float av[4] = {v.x, v.y, v.z, v.w};
    ushort h[4], l[4];
    #pragma unroll
    for (int j = 0; j < 4; ++j) {
        h[j] = f2bf_rne(av[j]);
        l[j] = f2bf_rne(av[j] - bf2f(h[j]));
    }
    size_t base = ((size_t)t * BB + b) * EMB + threadIdx.x * 4;
    *(ushort4*)(xs_hi + base) = make_ushort4(h[0], h[1], h[2], h[3]);
    *(ushort4*)(xs_lo + base) = make_ushort4(l[0], l[1], l[2], l[3]);
}

// ---------------------------------------------------------------------------
// k_attn: one block per batch element. ha -> logits -> softmax -> ctx (split).
// ---------------------------------------------------------------------------
__global__ __launch_bounds__(1024) void k_attn(
    const float* __restrict__ f, const float* __restrict__ fa,
    const float* __restrict__ hx,
    const float* __restrict__ W2, const float* __restrict__ b2,
    const float* __restrict__ V,
    ushort* __restrict__ ctx_hi, ushort* __restrict__ ctx_lo)
{
    __shared__ __align__(16) float smem[3072];
    const int b = blockIdx.x;
    const int tid = threadIdx.x;
    const int lane = tid & 63;
    const int wid = tid >> 6;

    float* hx_s = smem;          // 1024
    float* ha_s = smem + 1024;   // 512
    float* V_s  = smem + 1536;   // 512
    float* w_s  = smem + 2048;   // 256 (196 used)
    float* red  = smem + 2304;   // 256
    float* pc   = smem + 2560;   // 512

    hx_s[tid] = hx[b * HID + tid];
    if (tid < ATT) V_s[tid] = V[tid];
    __syncthreads();

    // ha[a] = hx . W2[a] + b2[a]
    for (int a = wid; a < ATT; a += 16) {
        const float4* wr = (const float4*)(W2 + (size_t)a * HID);
        float s = 0.f;
        #pragma unroll
        for (int q = 0; q < 4; ++q) {
            int i4 = q * 64 + lane;
            float4 w = wr[i4];
            float4 x = *(const float4*)&hx_s[i4 * 4];
            s += w.x*x.x + w.y*x.y + w.z*x.z + w.w*x.w;
        }
        #pragma unroll
        for (int off = 32; off > 0; off >>= 1) s += __shfl_down(s, off);
        if (lane == 0) ha_s[a] = s + b2[a];
    }
    __syncthreads();

    // logits[h] (bV omitted: softmax-invariant)
    for (int h = wid; h < HW; h += 16) {
        const float4* fr = (const float4*)(fa + ((size_t)b * HW + h) * ATT);
        float s = 0.f;
        #pragma unroll
        for (int q = 0; q < 2; ++q) {
            int i4 = q * 64 + lane;
            float4 fv = fr[i4];
            float4 hv = *(const float4*)&ha_s[i4 * 4];
            float4 vv = *(const float4*)&V_s[i4 * 4];
            s += tanh_fast(fv.x + hv.x) * vv.x + tanh_fast(fv.y + hv.y) * vv.y
               + tanh_fast(fv.z + hv.z) * vv.z + tanh_fast(fv.w + hv.w) * vv.w;
        }
        #pragma unroll
        for (int off = 32; off > 0; off >>= 1) s += __shfl_down(s, off);
        if (lane == 0) w_s[h] = s;
    }
    __syncthreads();

    // softmax over 196
    float v = (tid < HW) ? w_s[tid] : -INFINITY;
    if (tid < 256) red[tid] = v;
    __syncthreads();
    for (int s2 = 128; s2 > 0; s2 >>= 1) {
        if (tid < s2) red[tid] = fmaxf(red[tid], red[tid + s2]);
        __syncthreads();
    }
    float mx = red[0];
    __syncthreads();
    float e = (tid < HW) ? __expf(v - mx) : 0.f;
    if (tid < 256) red[tid] = e;
    __syncthreads();
    for (int s2 = 128; s2 > 0; s2 >>= 1) {
        if (tid < s2) red[tid] += red[tid + s2];
        __syncthreads();
    }
    float inv = 1.0f / red[0];
    if (tid < HW) w_s[tid] = e * inv;
    __syncthreads();

    // ctx[e] = sum_h w[h] * f[b][h][e]; write split-bf16
    {
        int e0 = tid & 511, grp = tid >> 9;
        const float* fb = f + (size_t)b * HW * EMB + e0;
        float s = 0.f;
        for (int h = grp; h < HW; h += 2)
            s = fmaf(w_s[h], fb[(size_t)h * EMB], s);
        if (grp) pc[e0] = s;
        __syncthreads();
        if (!grp) {
            float c = s + pc[e0];
            ushort ch = f2bf_rne(c);
            ctx_hi[b * EMB + e0] = ch;
            ctx_lo[b * EMB + e0] = f2bf_rne(c - bf2f(ch));
        }
    }
}

// ---------------------------------------------------------------------------
// k_gates: gates GEMM (split-bf16 MFMA) + fused LSTM pointwise.
// 64 blocks x 1024 threads. Block bk owns u-range [bk*16, +16) => 64 ncols
// (4 gates x 16 u). 16 waves = 4(mt) x 4(nt=gate): each wave one 16x16 tile,
// K=2048 in 3 segments [xs | ctx | hx]. A/B read straight from L2-cached
// bf16 planes. Epilogue: 16KB LDS gate exchange -> LSTM -> hx/cx/hx_all +
// next-step hx planes (parity double-buffered).
// ---------------------------------------------------------------------------
__global__ __launch_bounds__(1024) void k_gates(
    const ushort* __restrict__ xsh, const ushort* __restrict__ xsl,   // [64][512]
    const ushort* __restrict__ cth, const ushort* __restrict__ ctl,   // [64][512]
    const ushort* __restrict__ hxh, const ushort* __restrict__ hxl,   // [64][1024]
    const ushort* __restrict__ wihh, const ushort* __restrict__ wihl, // [4096][1024]
    const ushort* __restrict__ whhh, const ushort* __restrict__ whhl, // [4096][1024]
    const float* __restrict__ b_ih, const float* __restrict__ b_hh,
    float* __restrict__ hx, float* __restrict__ cx,
    ushort* __restrict__ nxh, ushort* __restrict__ nxl,               // next hx planes
    float* __restrict__ hx_all_t)                                     // [64][1024]
{
    __shared__ float sg[4][64][16];   // 16 KB
    const int tid = threadIdx.x, bk = blockIdx.x;
    const int lane = tid & 63, wid = tid >> 6;
    const int mt = wid & 3, nt = wid >> 2;
    const int l15 = lane & 15, g = lane >> 4;
    const int ra = mt * 16 + l15;                       // A row (batch)
    const int ncol = nt * 1024 + bk * 16 + l15;         // weight row
    const int koff = g * 8;

    f32x4 acc0 = {}, acc1 = {};

    // seg 0: xs, W_ih cols [0,512)
    {
        const ushort* ah = xsh + (size_t)ra * 512 + koff;
        const ushort* al = xsl + (size_t)ra * 512 + koff;
        const ushort* bh = wihh + (size_t)ncol * 1024 + koff;
        const ushort* bl = wihl + (size_t)ncol * 1024 + koff;
        #pragma unroll 4
        for (int kk = 0; kk < 16; ++kk) {
            bfrag a_h = *(const bfrag*)(ah + kk * 32);
            bfrag a_l = *(const bfrag*)(al + kk * 32);
            bfrag b_h = *(const bfrag*)(bh + kk * 32);
            bfrag b_l = *(const bfrag*)(bl + kk * 32);
            acc0 = __builtin_amdgcn_mfma_f32_16x16x32_bf16(a_h, b_h, acc0, 0, 0, 0);
            acc1 = __builtin_amdgcn_mfma_f32_16x16x32_bf16(a_h, b_l, acc1, 0, 0, 0);
            acc1 = __builtin_amdgcn_mfma_f32_16x16x32_bf16(a_l, b_h, acc1, 0, 0, 0);
        }
    }
    // seg 1: ctx, W_ih cols [512,1024)
    {
        const ushort* ah = cth + (size_t)ra * 512 + koff;
        const ushort* al = ctl + (size_t)ra * 512 + koff;
        const ushort* bh = wihh + (size_t)ncol * 1024 + 512 + koff;
        const ushort* bl = wihl + (size_t)ncol * 1024 + 512 + koff;
        #pragma unroll 4
        for (int kk = 0; kk < 16; ++kk) {
            bfrag a_h = *(const bfrag*)(ah + kk * 32);
            bfrag a_l = *(const bfrag*)(al + kk * 32);
            bfrag b_h = *(const bfrag*)(bh + kk * 32);
            bfrag b_l = *(const bfrag*)(bl + kk * 32);
            acc0 = __builtin_amdgcn_mfma_f32_16x16x32_bf16(a_h, b_h, acc0, 0, 0, 0);
            acc1 = __builtin_amdgcn_mfma_f32_16x16x32_bf16(a_h, b_l, acc1, 0, 0, 0);
            acc1 = __builtin_amdgcn_mfma_f32_16x16x32_bf16(a_l, b_h, acc1, 0, 0, 0);
        }
    }
    // seg 2: hx planes, W_hh cols [0,1024)
    {
        const ushort* ah = hxh + (size_t)ra * 1024 + koff;
        const ushort* al = hxl + (size_t)ra * 1024 + koff;
        const ushort* bh = whhh + (size_t)ncol * 1024 + koff;
        const ushort* bl = whhl + (size_t)ncol * 1024 + koff;
        #pragma unroll 4
        for (int kk = 0; kk < 32; ++kk) {
            bfrag a_h = *(const bfrag*)(ah + kk * 32);
            bfrag a_l = *(const bfrag*)(al + kk * 32);
            bfrag b_h = *(const bfrag*)(bh + kk * 32);
            bfrag b_l = *(const bfrag*)(bl + kk * 32);
            acc0 = __builtin_amdgcn_mfma_f32_16x16x32_bf16(a_h, b_h, acc0, 0, 0, 0);
            acc1 = __builtin_amdgcn_mfma_f32_16x16x32_bf16(a_h, b_l, acc1, 0, 0, 0);
            acc1 = __builtin_amdgcn_mfma_f32_16x16x32_bf16(a_l, b_h, acc1, 0, 0, 0);
        }
    }

    // C tile -> LDS: row = mt*16 + g*4 + r (batch), col l15 (u), gate nt
    #pragma unroll
    for (int r = 0; r < 4; ++r)
        sg[nt][mt * 16 + g * 4 + r][l15] = acc0[r] + acc1[r];
    __syncthreads();

    // fused LSTM: thread -> (b, uloc)
    {
        int b = tid >> 4, uloc = tid & 15;
        int u = bk * 16 + uloc;
        float gi = sg[0][b][uloc] + b_ih[u]        + b_hh[u];
        float gf = sg[1][b][uloc] + b_ih[1024 + u] + b_hh[1024 + u];
        float gg = sg[2][b][uloc] + b_ih[2048 + u] + b_hh[2048 + u];
        float go = sg[3][b][uloc] + b_ih[3072 + u] + b_hh[3072 + u];
        int idx = b * 1024 + u;
        float c = sigmoid_fast(gf) * cx[idx] + sigmoid_fast(gi) * tanh_fast(gg);
        float h = sigmoid_fast(go) * tanh_fast(c);
        cx[idx] = c;
        hx[idx] = h;
        hx_all_t[idx] = h;
        ushort hh = f2bf_rne(h);
        nxh[idx] = hh;
        nxl[idx] = f2bf_rne(h - bf2f(hh));
    }
}

// ---------------------------------------------------------------------------
extern "C" void kernel_launch(void* const* d_in, const int* in_sizes, int n_in,
                              void* d_out, int out_size, void* d_ws, size_t ws_size,
                              hipStream_t stream) {
    const float* features = (const float*)d_in[0];
    const int*   captions = (const int*)d_in[1];
    const float* E      = (const float*)d_in[3];
    const float* W_feat = (const float*)d_in[4];
    const float* b_feat = (const float*)d_in[5];
    const float* W1     = (const float*)d_in[6];
    const float* b1     = (const float*)d_in[7];
    const float* W2     = (const float*)d_in[8];
    const float* b2     = (const float*)d_in[9];
    const float* V      = (const float*)d_in[10];
    // d_in[11] bV: softmax-invariant, unused
    const float* W_hi   = (const float*)d_in[12];
    const float* b_hi   = (const float*)d_in[13];
    const float* W_ci   = (const float*)d_in[14];
    const float* b_ci   = (const float*)d_in[15];
    const float* W_ih   = (const float*)d_in[16];
    const float* b_ih   = (const float*)d_in[17];
    const float* W_hh   = (const float*)d_in[18];
    const float* b_hh   = (const float*)d_in[19];
    const float* W_out  = (const float*)d_in[20];
    const float* b_out  = (const float*)d_in[21];
    float* out = (float*)d_out;

    // ---- workspace layout ----
    float* ws = (float*)d_ws;
    float* f_buf   = ws;                          // 6,422,528
    float* fa_buf  = f_buf + 6422528;             // 6,422,528
    float* fmean   = fa_buf + 6422528;            // 32,768
    float* hx      = fmean + 32768;               // 65,536
    float* cx      = hx + 65536;                  // 65,536
    float* hx_all  = cx + 65536;                  // 1,310,720
    ushort* p = (ushort*)(hx_all + 1310720);
    ushort* wfeat_hi = p;            p += 1048576;
    ushort* wfeat_lo = p;            p += 1048576;
    ushort* w1_hi    = p;            p += 262144;
    ushort* w1_lo    = p;            p += 262144;
    ushort* wih_hi   = p;            p += 4194304;
    ushort* wih_lo   = p;            p += 4194304;
    ushort* whh_hi   = p;            p += 4194304;
    ushort* whh_lo   = p;            p += 4194304;
    ushort* xs_hi    = p;            p += 622592;
    ushort* xs_lo    = p;            p += 622592;
    ushort* ctx_hi   = p;            p += 32768;
    ushort* ctx_lo   = p;            p += 32768;
    ushort* hxp      = p;            p += 262144;   // [2 bufs][hi|lo][65536]
    // W_out planes reuse f_buf+fa_buf region after the step loop (41MB <= 51MB)
    ushort* wout_hi = (ushort*)f_buf;
    ushort* wout_lo = wout_hi + 10240000;

    // ---- precompute ----
    k_split<<<1048576 / 4 / 256, 256, 0, stream>>>(W_feat, wfeat_hi, wfeat_lo, 1048576);
    k_split<<<262144 / 4 / 256, 256, 0, stream>>>(W1, w1_hi, w1_lo, 262144);
    k_split<<<4194304 / 4 / 256, 256, 0, stream>>>(W_ih, wih_hi, wih_lo, 4194304);
    k_split<<<4194304 / 4 / 256, 256, 0, stream>>>(W_hh, whh_hi, whh_lo, 4194304);
    // f = features @ W_feat^T + b_feat  [12544,512], K=2048
    mfma_nt<2><<<dim3(4, 196), 256, 0, stream>>>(
        features, wfeat_hi, wfeat_lo, b_feat, f_buf, 12544, 512, 2048, 512);
    // fa = f @ W1^T + b1  [12544,512], K=512
    mfma_nt<2><<<dim3(4, 196), 256, 0, stream>>>(
        f_buf, w1_hi, w1_lo, b1, fa_buf, 12544, 512, 512, 512);
    k_fmean<<<BB, 256, 0, stream>>>(f_buf, fmean);
    k_init<<<BB, 256, 0, stream>>>(fmean, W_hi, b_hi, W_ci, b_ci, hx, cx);
    k_split<<<65536 / 4 / 256, 256, 0, stream>>>(hx, hxp, hxp + 65536, 65536);
    k_embed_split<<<STEPS * BB, 128, 0, stream>>>(captions, E, xs_hi, xs_lo);

    // ---- recurrent steps: 2 dispatches per step ----
    for (int t = 0; t < STEPS; ++t) {
        ushort* hx_rd = hxp + (size_t)(t & 1) * 131072;
        ushort* hx_wr = hxp + (size_t)((t + 1) & 1) * 131072;
        k_attn<<<BB, 1024, 0, stream>>>(
            f_buf, fa_buf, hx, W2, b2, V, ctx_hi, ctx_lo);
        k_gates<<<BB, 1024, 0, stream>>>(
            xs_hi + (size_t)t * BB * EMB, xs_lo + (size_t)t * BB * EMB,
            ctx_hi, ctx_lo, hx_rd, hx_rd + 65536,
            wih_hi, wih_lo, whh_hi, whh_lo, b_ih, b_hh,
            hx, cx, hx_wr, hx_wr + 65536,
            hx_all + (size_t)t * BB * HID);
    }

    // ---- vocab projection over all steps: [1216,10000], K=1024 ----
    k_split<<<10240000 / 4 / 256, 256, 0, stream>>>(W_out, wout_hi, wout_lo, 10240000);
    mfma_nt<4><<<dim3(40, 20), 256, 0, stream>>>(
        hx_all, wout_hi, wout_lo, b_out, out, STEPS * BB, VOCAB, HID, VOCAB);
}

// Round 7
// 2240.298 us; speedup vs baseline: 3.6351x; 1.8910x over previous
//
#include <hip/hip_runtime.h>
#include <hip/hip_bf16.h>
#include <math.h>

#define BB 64
#define HW 196
#define FEAT 2048
#define EMB 512
#define HID 1024
#define ATT 512
#define VOCAB 10000
#define TT 20
#define STEPS 19

using bfrag = __attribute__((ext_vector_type(8))) short;   // 8 bf16 = 4 VGPR
using f32x4 = __attribute__((ext_vector_type(4))) float;

__device__ __forceinline__ float sigmoid_fast(float x) { return 1.0f / (1.0f + __expf(-x)); }
__device__ __forceinline__ float tanh_fast(float x) {
    float e = __expf(2.0f * x);
    return 1.0f - 2.0f / (e + 1.0f);
}
__device__ __forceinline__ ushort f2bf_rne(float f) {
    unsigned u = __float_as_uint(f);
    unsigned r = (u + 0x7FFFu + ((u >> 16) & 1u)) >> 16;
    return (ushort)r;
}
__device__ __forceinline__ float bf2f(ushort h) {
    return __uint_as_float(((unsigned)h) << 16);
}

// ---------------------------------------------------------------------------
// fp32 -> split bf16 planes: x = hi + lo.  n % 1024 == 0.
// ---------------------------------------------------------------------------
__global__ __launch_bounds__(256) void k_split(const float* __restrict__ x,
                                               ushort* __restrict__ hi,
                                               ushort* __restrict__ lo, int n)
{
    int i4 = (blockIdx.x * 256 + threadIdx.x) * 4;
    if (i4 >= n) return;
    float4 v = *(const float4*)(x + i4);
    float av[4] = {v.x, v.y, v.z, v.w};
    #pragma unroll
    for (int j = 0; j < 4; ++j) {
        ushort h = f2bf_rne(av[j]);
        hi[i4 + j] = h;
        lo[i4 + j] = f2bf_rne(av[j] - bf2f(h));
    }
}

// ---------------------------------------------------------------------------
// mfma_f: split-bf16 NT GEMM, 128(M) x 128(N) tile, BK=32, 4 waves (2x2 of
// 64x64). A fp32 converted during staging; B pre-split planes. 3-term.
// C/D 16x16 layout: col = lane&15, row = (lane>>4)*4 + reg.
// grid = (ceil(N/128), ceil(M/128)).
// ---------------------------------------------------------------------------
__global__ __launch_bounds__(256) void mfma_f(
    const float* __restrict__ A,
    const ushort* __restrict__ Bhi, const ushort* __restrict__ Blo,
    const float* __restrict__ bias, float* __restrict__ C,
    int Mvalid, int N, int K, int ldc)
{
    __shared__ __align__(16) ushort sAh[4][128][8];
    __shared__ __align__(16) ushort sAl[4][128][8];
    __shared__ __align__(16) ushort sBh[4][128][8];
    __shared__ __align__(16) ushort sBl[4][128][8];

    const int tid = threadIdx.x;
    const int m0 = blockIdx.y * 128;
    const int n0 = blockIdx.x * 128;

    const int srow = tid >> 1;              // 0..127
    const int shalf = tid & 1;              // 0,1 -> k 0..15 / 16..31
    const int arow = min(m0 + srow, Mvalid - 1);
    const int brow = min(n0 + srow, N - 1);
    const float* ap = A + (size_t)arow * K + shalf * 16;
    const ushort* bhp = Bhi + (size_t)brow * K + shalf * 16;
    const ushort* blp = Blo + (size_t)brow * K + shalf * 16;

    const int lane = tid & 63;
    const int w = tid >> 6;
    const int mr0 = (w & 1) * 64;
    const int nc0 = (w >> 1) * 64;
    const int g = lane >> 4, l15 = lane & 15;

    f32x4 acc[4][4] = {};

    for (int k0 = 0; k0 < K; k0 += 32) {
        __syncthreads();
        {   // A: 16 fp32 -> hi/lo bfrag pair
            float av[16];
            *(float4*)(av)      = *(const float4*)(ap + k0);
            *(float4*)(av + 4)  = *(const float4*)(ap + k0 + 4);
            *(float4*)(av + 8)  = *(const float4*)(ap + k0 + 8);
            *(float4*)(av + 12) = *(const float4*)(ap + k0 + 12);
            bfrag vh0, vl0, vh1, vl1;
            #pragma unroll
            for (int j = 0; j < 8; ++j) {
                ushort h = f2bf_rne(av[j]);
                vh0[j] = (short)h; vl0[j] = (short)f2bf_rne(av[j] - bf2f(h));
                ushort h2 = f2bf_rne(av[8 + j]);
                vh1[j] = (short)h2; vl1[j] = (short)f2bf_rne(av[8 + j] - bf2f(h2));
            }
            int kb = shalf * 2;
            *(bfrag*)&sAh[kb][srow][0] = vh0;  *(bfrag*)&sAh[kb + 1][srow][0] = vh1;
            *(bfrag*)&sAl[kb][srow][0] = vl0;  *(bfrag*)&sAl[kb + 1][srow][0] = vl1;
        }
        {   // B planes: 2 bfrags each
            int kb = shalf * 2;
            *(bfrag*)&sBh[kb][srow][0]     = *(const bfrag*)(bhp + k0);
            *(bfrag*)&sBh[kb + 1][srow][0] = *(const bfrag*)(bhp + k0 + 8);
            *(bfrag*)&sBl[kb][srow][0]     = *(const bfrag*)(blp + k0);
            *(bfrag*)&sBl[kb + 1][srow][0] = *(const bfrag*)(blp + k0 + 8);
        }
        __syncthreads();

        bfrag ah[4], al[4], bh[4], bl[4];
        #pragma unroll
        for (int s = 0; s < 4; ++s) {
            ah[s] = *(const bfrag*)&sAh[g][mr0 + s * 16 + l15][0];
            al[s] = *(const bfrag*)&sAl[g][mr0 + s * 16 + l15][0];
        }
        #pragma unroll
        for (int u = 0; u < 4; ++u) {
            bh[u] = *(const bfrag*)&sBh[g][nc0 + u * 16 + l15][0];
            bl[u] = *(const bfrag*)&sBl[g][nc0 + u * 16 + l15][0];
        }
        #pragma unroll
        for (int s = 0; s < 4; ++s)
            #pragma unroll
            for (int u = 0; u < 4; ++u) {
                acc[s][u] = __builtin_amdgcn_mfma_f32_16x16x32_bf16(ah[s], bh[u], acc[s][u], 0, 0, 0);
                acc[s][u] = __builtin_amdgcn_mfma_f32_16x16x32_bf16(ah[s], bl[u], acc[s][u], 0, 0, 0);
                acc[s][u] = __builtin_amdgcn_mfma_f32_16x16x32_bf16(al[s], bh[u], acc[s][u], 0, 0, 0);
            }
    }

    #pragma unroll
    for (int s = 0; s < 4; ++s)
        #pragma unroll
        for (int u = 0; u < 4; ++u) {
            int col = n0 + nc0 + u * 16 + l15;
            if (col < N) {
                float bv = bias[col];
                #pragma unroll
                for (int r = 0; r < 4; ++r) {
                    int row = m0 + mr0 + s * 16 + g * 4 + r;
                    if (row < Mvalid)
                        C[(size_t)row * ldc + col] = acc[s][u][r] + bv;
                }
            }
        }
}

// ---------------------------------------------------------------------------
__global__ __launch_bounds__(256) void k_fmean(const float* __restrict__ f,
                                               float* __restrict__ fmean)
{
    int b = blockIdx.x, tid = threadIdx.x;
    for (int e = tid; e < EMB; e += 256) {
        const float* fb = f + (size_t)b * HW * EMB + e;
        float s = 0.f;
        for (int h = 0; h < HW; ++h) s += fb[(size_t)h * EMB];
        fmean[b * EMB + e] = s * (1.0f / HW);
    }
}

__global__ __launch_bounds__(256) void k_init(
    const float* __restrict__ fmean,
    const float* __restrict__ W_hi, const float* __restrict__ b_hi,
    const float* __restrict__ W_ci, const float* __restrict__ b_ci,
    float* __restrict__ hx, float* __restrict__ cx)
{
    int b = blockIdx.x, tid = threadIdx.x;
    __shared__ float fm[EMB];
    for (int i = tid; i < EMB; i += 256) fm[i] = fmean[b * EMB + i];
    __syncthreads();
    for (int u = tid; u < HID; u += 256) {
        const float4* w1 = (const float4*)(W_hi + (size_t)u * EMB);
        const float4* w2 = (const float4*)(W_ci + (size_t)u * EMB);
        float a1 = b_hi[u], a2 = b_ci[u];
        for (int k = 0; k < EMB / 4; ++k) {
            float4 y1 = w1[k], y2 = w2[k];
            float x0 = fm[4*k], x1 = fm[4*k+1], x2 = fm[4*k+2], x3 = fm[4*k+3];
            a1 += x0*y1.x + x1*y1.y + x2*y1.z + x3*y1.w;
            a2 += x0*y2.x + x1*y2.y + x2*y2.z + x3*y2.w;
        }
        hx[b * HID + u] = a1;
        cx[b * HID + u] = a2;
    }
}

// xs_hi/lo[t*64+b][:] = split(E[captions[b][t]][:])
__global__ __launch_bounds__(128) void k_embed_split(
    const int* __restrict__ cap, const float* __restrict__ E,
    ushort* __restrict__ xs_hi, ushort* __restrict__ xs_lo)
{
    int blk = blockIdx.x;
    int t = blk / BB, b = blk % BB;
    int c = cap[b * TT + t];
    float4 v = ((const float4*)(E + (size_t)c * EMB))[threadIdx.x];
    float av[4] = {v.x, v.y, v.z, v.w};
    ushort h[4], l[4];
    #pragma unroll
    for (int j = 0; j < 4; ++j) {
        h[j] = f2bf_rne(av[j]);
        l[j] = f2bf_rne(av[j] - bf2f(h[j]));
    }
    size_t base = ((size_t)t * BB + b) * EMB + threadIdx.x * 4;
    *(ushort4*)(xs_hi + base) = make_ushort4(h[0], h[1], h[2], h[3]);
    *(ushort4*)(xs_lo + base) = make_ushort4(l[0], l[1], l[2], l[3]);
}

// ---------------------------------------------------------------------------
// k_ha: ha[b][a] = hx[b].W2[a] + b2[a].  grid 256: block -> 16 a's x 8 b's.
// W2 total traffic ~2MB/step (L2-shared), hx 32KB/block.
// ---------------------------------------------------------------------------
__global__ __launch_bounds__(256) void k_ha(
    const float* __restrict__ hx, const float* __restrict__ W2,
    const float* __restrict__ b2, float* __restrict__ ha)
{
    __shared__ __align__(16) float hx_s[8][1028];  // +4 pad: spreads b_i banks
    __shared__ float part[256];
    const int tid = threadIdx.x;
    const int a0 = (blockIdx.x >> 3) * 16;
    const int b0 = (blockIdx.x & 7) * 8;

    // stage 8 hx rows
    for (int i = tid; i < 8 * 256; i += 256) {
        int r = i >> 8, c4 = i & 255;
        *(float4*)&hx_s[r][c4 * 4] = *(const float4*)(hx + (size_t)(b0 + r) * HID + c4 * 4);
    }
    __syncthreads();

    const int a_i = tid >> 4;
    const int b_i = (tid >> 1) & 7;
    const int half = tid & 1;
    const float4* wr = (const float4*)(W2 + (size_t)(a0 + a_i) * HID + half * 512);
    const float* xr = &hx_s[b_i][half * 512];
    float s = 0.f;
    #pragma unroll 8
    for (int i = 0; i < 128; ++i) {
        float4 w = wr[i];
        float4 x = *(const float4*)(xr + i * 4);
        s += w.x*x.x + w.y*x.y + w.z*x.z + w.w*x.w;
    }
    part[tid] = s;
    __syncthreads();
    if (!half)
        ha[(size_t)(b0 + b_i) * ATT + a0 + a_i] = part[tid] + part[tid + 1] + b2[a0 + a_i];
}

// ---------------------------------------------------------------------------
// k_logits: grid 256 (b*4+q, 49 h each).
// ---------------------------------------------------------------------------
__global__ __launch_bounds__(256) void k_logits(
    const float* __restrict__ fa, const float* __restrict__ ha,
    const float* __restrict__ V, float* __restrict__ logits)
{
    int blk = blockIdx.x;
    int b = blk >> 2, q = blk & 3;
    int tid = threadIdx.x;
    __shared__ float ha_s[ATT];
    __shared__ float V_s[ATT];
    for (int i = tid; i < ATT; i += 256) { ha_s[i] = ha[b * ATT + i]; V_s[i] = V[i]; }
    __syncthreads();

    int wid = tid >> 6, lane = tid & 63;
    for (int h = q * 49 + wid; h < q * 49 + 49; h += 4) {
        const float* far = fa + ((size_t)b * HW + h) * ATT;
        float s = 0.f;
        #pragma unroll
        for (int i = 0; i < ATT / 64; ++i) {
            int a = lane + (i << 6);
            s += tanh_fast(far[a] + ha_s[a]) * V_s[a];
        }
        #pragma unroll
        for (int off = 32; off > 0; off >>= 1) s += __shfl_down(s, off);
        if (lane == 0) logits[b * HW + h] = s;
    }
}

// ---------------------------------------------------------------------------
// k_ctx: grid 256 (b*4+eg, 128 e each). Recompute softmax; ctx -> planes.
// ---------------------------------------------------------------------------
__global__ __launch_bounds__(256) void k_ctx(
    const float* __restrict__ logits, const float* __restrict__ f,
    ushort* __restrict__ ctx_hi, ushort* __restrict__ ctx_lo)
{
    int blk = blockIdx.x;
    int b = blk >> 2, eg = blk & 3;
    int tid = threadIdx.x;
    __shared__ float w_s[HW];
    __shared__ float red_s[256];
    __shared__ float part[128];

    float v = (tid < HW) ? logits[b * HW + tid] : -INFINITY;
    red_s[tid] = v; __syncthreads();
    for (int s = 128; s > 0; s >>= 1) {
        if (tid < s) red_s[tid] = fmaxf(red_s[tid], red_s[tid + s]);
        __syncthreads();
    }
    float mx = red_s[0]; __syncthreads();
    float e = (tid < HW) ? __expf(v - mx) : 0.f;
    red_s[tid] = e; __syncthreads();
    for (int s = 128; s > 0; s >>= 1) {
        if (tid < s) red_s[tid] += red_s[tid + s];
        __syncthreads();
    }
    float inv = 1.0f / red_s[0];
    if (tid < HW) w_s[tid] = e * inv;
    __syncthreads();

    int e0 = (eg << 7) + (tid & 127);
    int half = tid >> 7;
    const float* fb = f + (size_t)b * HW * EMB + e0;
    float s = 0.f;
    int h0 = half * 98;
    for (int h = h0; h < h0 + 98; ++h)
        s = fmaf(w_s[h], fb[(size_t)h * EMB], s);
    if (half) part[tid & 127] = s;
    __syncthreads();
    if (!half) {
        float c = s + part[tid];
        ushort ch = f2bf_rne(c);
        ctx_hi[b * EMB + e0] = ch;
        ctx_lo[b * EMB + e0] = f2bf_rne(c - bf2f(ch));
    }
}

// ---------------------------------------------------------------------------
// k_gates_m: gates[64][4096] via split-bf16 MFMA. grid 256 x 256 thr.
// Block bk owns 16 ncols [bk*16,+16). 4 waves = 4 m-tiles (16 batch rows).
// K = 2048 segments [xs | ctx | hx]. Weights disjoint per block (128KB).
// ---------------------------------------------------------------------------
__global__ __launch_bounds__(256) void k_gates_m(
    const ushort* __restrict__ xsh, const ushort* __restrict__ xsl,   // [64][512]
    const ushort* __restrict__ cth, const ushort* __restrict__ ctl,   // [64][512]
    const ushort* __restrict__ hxh, const ushort* __restrict__ hxl,   // [64][1024]
    const ushort* __restrict__ wihh, const ushort* __restrict__ wihl, // [4096][1024]
    const ushort* __restrict__ whhh, const ushort* __restrict__ whhl, // [4096][1024]
    float* __restrict__ gates)                                        // [64][4096]
{
    const int tid = threadIdx.x, bk = blockIdx.x;
    const int lane = tid & 63, mt = tid >> 6;
    const int l15 = lane & 15, g = lane >> 4;
    const int arow = mt * 16 + l15;            // batch row
    const int ncol = bk * 16 + l15;            // weight row
    const int koff = g * 8;

    f32x4 acc0 = {}, acc1 = {};

    // seg 0: xs . W_ih[:, 0:512)
    {
        const ushort* ah = xsh + (size_t)arow * 512 + koff;
        const ushort* al = xsl + (size_t)arow * 512 + koff;
        const ushort* bh = wihh + (size_t)ncol * 1024 + koff;
        const ushort* bl = wihl + (size_t)ncol * 1024 + koff;
        #pragma unroll 4
        for (int kk = 0; kk < 16; ++kk) {
            bfrag a_h = *(const bfrag*)(ah + kk * 32);
            bfrag a_l = *(const bfrag*)(al + kk * 32);
            bfrag b_h = *(const bfrag*)(bh + kk * 32);
            bfrag b_l = *(const bfrag*)(bl + kk * 32);
            acc0 = __builtin_amdgcn_mfma_f32_16x16x32_bf16(a_h, b_h, acc0, 0, 0, 0);
            acc1 = __builtin_amdgcn_mfma_f32_16x16x32_bf16(a_h, b_l, acc1, 0, 0, 0);
            acc1 = __builtin_amdgcn_mfma_f32_16x16x32_bf16(a_l, b_h, acc1, 0, 0, 0);
        }
    }
    // seg 1: ctx . W_ih[:, 512:1024)
    {
        const ushort* ah = cth + (size_t)arow * 512 + koff;
        const ushort* al = ctl + (size_t)arow * 512 + koff;
        const ushort* bh = wihh + (size_t)ncol * 1024 + 512 + koff;
        const ushort* bl = wihl + (size_t)ncol * 1024 + 512 + koff;
        #pragma unroll 4
        for (int kk = 0; kk < 16; ++kk) {
            bfrag a_h = *(const bfrag*)(ah + kk * 32);
            bfrag a_l = *(const bfrag*)(al + kk * 32);
            bfrag b_h = *(const bfrag*)(bh + kk * 32);
            bfrag b_l = *(const bfrag*)(bl + kk * 32);
            acc0 = __builtin_amdgcn_mfma_f32_16x16x32_bf16(a_h, b_h, acc0, 0, 0, 0);
            acc1 = __builtin_amdgcn_mfma_f32_16x16x32_bf16(a_h, b_l, acc1, 0, 0, 0);
            acc1 = __builtin_amdgcn_mfma_f32_16x16x32_bf16(a_l, b_h, acc1, 0, 0, 0);
        }
    }
    // seg 2: hx . W_hh
    {
        const ushort* ah = hxh + (size_t)arow * 1024 + koff;
        const ushort* al = hxl + (size_t)arow * 1024 + koff;
        const ushort* bh = whhh + (size_t)ncol * 1024 + koff;
        const ushort* bl = whhl + (size_t)ncol * 1024 + koff;
        #pragma unroll 4
        for (int kk = 0; kk < 32; ++kk) {
            bfrag a_h = *(const bfrag*)(ah + kk * 32);
            bfrag a_l = *(const bfrag*)(al + kk * 32);
            bfrag b_h = *(const bfrag*)(bh + kk * 32);
            bfrag b_l = *(const bfrag*)(bl + kk * 32);
            acc0 = __builtin_amdgcn_mfma_f32_16x16x32_bf16(a_h, b_h, acc0, 0, 0, 0);
            acc1 = __builtin_amdgcn_mfma_f32_16x16x32_bf16(a_h, b_l, acc1, 0, 0, 0);
            acc1 = __builtin_amdgcn_mfma_f32_16x16x32_bf16(a_l, b_h, acc1, 0, 0, 0);
        }
    }

    #pragma unroll
    for (int r = 0; r < 4; ++r) {
        int row = mt * 16 + g * 4 + r;
        gates[(size_t)row * 4096 + ncol] = acc0[r] + acc1[r];
    }
}

// ---------------------------------------------------------------------------
// k_lstm: pointwise; writes hx fp32, hx planes (single buffer), cx, hx_all.
// ---------------------------------------------------------------------------
__global__ __launch_bounds__(256) void k_lstm(
    const float* __restrict__ gates, const float* __restrict__ b_ih,
    const float* __restrict__ b_hh, float* __restrict__ hx,
    float* __restrict__ cx, ushort* __restrict__ hxh, ushort* __restrict__ hxl,
    float* __restrict__ hx_all_t)
{
    int idx = blockIdx.x * 256 + threadIdx.x;
    int b = idx >> 10, u = idx & 1023;
    const float* gr = gates + (size_t)b * 4096;
    float gi = gr[u]        + b_ih[u]        + b_hh[u];
    float gf = gr[1024 + u] + b_ih[1024 + u] + b_hh[1024 + u];
    float gg = gr[2048 + u] + b_ih[2048 + u] + b_hh[2048 + u];
    float go = gr[3072 + u] + b_ih[3072 + u] + b_hh[3072 + u];
    float c = sigmoid_fast(gf) * cx[idx] + sigmoid_fast(gi) * tanh_fast(gg);
    float h = sigmoid_fast(go) * tanh_fast(c);
    cx[idx] = c;
    hx[idx] = h;
    hx_all_t[idx] = h;
    ushort hh = f2bf_rne(h);
    hxh[idx] = hh;
    hxl[idx] = f2bf_rne(h - bf2f(hh));
}

// ---------------------------------------------------------------------------
extern "C" void kernel_launch(void* const* d_in, const int* in_sizes, int n_in,
                              void* d_out, int out_size, void* d_ws, size_t ws_size,
                              hipStream_t stream) {
    const float* features = (const float*)d_in[0];
    const int*   captions = (const int*)d_in[1];
    const float* E      = (const float*)d_in[3];
    const float* W_feat = (const float*)d_in[4];
    const float* b_feat = (const float*)d_in[5];
    const float* W1     = (const float*)d_in[6];
    const float* b1     = (const float*)d_in[7];
    const float* W2     = (const float*)d_in[8];
    const float* b2     = (const float*)d_in[9];
    const float* V      = (const float*)d_in[10];
    // d_in[11] bV: softmax-invariant, unused
    const float* W_hi   = (const float*)d_in[12];
    const float* b_hi   = (const float*)d_in[13];
    const float* W_ci   = (const float*)d_in[14];
    const float* b_ci   = (const float*)d_in[15];
    const float* W_ih   = (const float*)d_in[16];
    const float* b_ih   = (const float*)d_in[17];
    const float* W_hh   = (const float*)d_in[18];
    const float* b_hh   = (const float*)d_in[19];
    const float* W_out  = (const float*)d_in[20];
    const float* b_out  = (const float*)d_in[21];
    float* out = (float*)d_out;

    // ---- workspace layout ----
    float* ws = (float*)d_ws;
    float* f_buf   = ws;                          // 6,422,528
    float* fa_buf  = f_buf + 6422528;             // 6,422,528
    float* fmean   = fa_buf + 6422528;            // 32,768
    float* hx      = fmean + 32768;               // 65,536
    float* cx      = hx + 65536;                  // 65,536
    float* hx_all  = cx + 65536;                  // 1,310,720
    float* ha      = hx_all + 1310720;            // 32,768
    float* logits  = ha + 32768;                  // 12,544
    float* gates   = logits + 12544;              // 262,144
    ushort* p = (ushort*)(gates + 262144);
    ushort* wfeat_hi = p;            p += 1048576;
    ushort* wfeat_lo = p;            p += 1048576;
    ushort* w1_hi    = p;            p += 262144;
    ushort* w1_lo    = p;            p += 262144;
    ushort* wih_hi   = p;            p += 4194304;
    ushort* wih_lo   = p;            p += 4194304;
    ushort* whh_hi   = p;            p += 4194304;
    ushort* whh_lo   = p;            p += 4194304;
    ushort* xs_hi    = p;            p += 622592;
    ushort* xs_lo    = p;            p += 622592;
    ushort* ctx_hi   = p;            p += 32768;
    ushort* ctx_lo   = p;            p += 32768;
    ushort* hxp_hi   = p;            p += 65536;
    ushort* hxp_lo   = p;            p += 65536;
    // W_out planes reuse f_buf+fa_buf region after the step loop (41MB <= 51MB)
    ushort* wout_hi = (ushort*)f_buf;
    ushort* wout_lo = wout_hi + 10240000;

    // ---- precompute ----
    k_split<<<1048576 / 4 / 256, 256, 0, stream>>>(W_feat, wfeat_hi, wfeat_lo, 1048576);
    k_split<<<262144 / 4 / 256, 256, 0, stream>>>(W1, w1_hi, w1_lo, 262144);
    k_split<<<4194304 / 4 / 256, 256, 0, stream>>>(W_ih, wih_hi, wih_lo, 4194304);
    k_split<<<4194304 / 4 / 256, 256, 0, stream>>>(W_hh, whh_hi, whh_lo, 4194304);
    // f = features @ W_feat^T + b_feat  [12544,512], K=2048
    mfma_f<<<dim3(4, 98), 256, 0, stream>>>(
        features, wfeat_hi, wfeat_lo, b_feat, f_buf, 12544, 512, 2048, 512);
    // fa = f @ W1^T + b1  [12544,512], K=512
    mfma_f<<<dim3(4, 98), 256, 0, stream>>>(
        f_buf, w1_hi, w1_lo, b1, fa_buf, 12544, 512, 512, 512);
    k_fmean<<<BB, 256, 0, stream>>>(f_buf, fmean);
    k_init<<<BB, 256, 0, stream>>>(fmean, W_hi, b_hi, W_ci, b_ci, hx, cx);
    k_split<<<65536 / 4 / 256, 256, 0, stream>>>(hx, hxp_hi, hxp_lo, 65536);
    k_embed_split<<<STEPS * BB, 128, 0, stream>>>(captions, E, xs_hi, xs_lo);

    // ---- recurrent steps: 5 full-chip dispatches per step ----
    for (int t = 0; t < STEPS; ++t) {
        k_ha<<<256, 256, 0, stream>>>(hx, W2, b2, ha);
        k_logits<<<256, 256, 0, stream>>>(fa_buf, ha, V, logits);
        k_ctx<<<256, 256, 0, stream>>>(logits, f_buf, ctx_hi, ctx_lo);
        k_gates_m<<<256, 256, 0, stream>>>(
            xs_hi + (size_t)t * BB * EMB, xs_lo + (size_t)t * BB * EMB,
            ctx_hi, ctx_lo, hxp_hi, hxp_lo,
            wih_hi, wih_lo, whh_hi, whh_lo, gates);
        k_lstm<<<256, 256, 0, stream>>>(
            gates, b_ih, b_hh, hx, cx, hxp_hi, hxp_lo,
            hx_all + (size_t)t * BB * HID);
    }

    // ---- vocab projection over all steps: [1216,10000], K=1024 ----
    k_split<<<10240000 / 4 / 256, 256, 0, stream>>>(W_out, wout_hi, wout_lo, 10240000);
    mfma_f<<<dim3(79, 10), 256, 0, stream>>>(
        hx_all, wout_hi, wout_lo, b_out, out, STEPS * BB, VOCAB, HID, VOCAB);
}

// Round 8
// 1886.590 us; speedup vs baseline: 4.3166x; 1.1875x over previous
//
#include <hip/hip_runtime.h>
#include <hip/hip_bf16.h>
#include <math.h>

#define BB 64
#define HW 196
#define FEAT 2048
#define EMB 512
#define HID 1024
#define ATT 512
#define VOCAB 10000
#define TT 20
#define STEPS 19

using bfrag = __attribute__((ext_vector_type(8))) short;   // 8 bf16 = 4 VGPR
using f32x4 = __attribute__((ext_vector_type(4))) float;

__device__ __forceinline__ float sigmoid_fast(float x) { return 1.0f / (1.0f + __expf(-x)); }
__device__ __forceinline__ float tanh_fast(float x) {
    float e = __expf(2.0f * x);
    return 1.0f - 2.0f / (e + 1.0f);
}
__device__ __forceinline__ ushort f2bf_rne(float f) {
    unsigned u = __float_as_uint(f);
    unsigned r = (u + 0x7FFFu + ((u >> 16) & 1u)) >> 16;
    return (ushort)r;
}
__device__ __forceinline__ float bf2f(ushort h) {
    return __uint_as_float(((unsigned)h) << 16);
}

// ---------------------------------------------------------------------------
// fp32 -> split bf16 planes: x = hi + lo.  n % 1024 == 0.
// ---------------------------------------------------------------------------
__global__ __launch_bounds__(256) void k_split(const float* __restrict__ x,
                                               ushort* __restrict__ hi,
                                               ushort* __restrict__ lo, int n)
{
    int i4 = (blockIdx.x * 256 + threadIdx.x) * 4;
    if (i4 >= n) return;
    float4 v = *(const float4*)(x + i4);
    float av[4] = {v.x, v.y, v.z, v.w};
    #pragma unroll
    for (int j = 0; j < 4; ++j) {
        ushort h = f2bf_rne(av[j]);
        hi[i4 + j] = h;
        lo[i4 + j] = f2bf_rne(av[j] - bf2f(h));
    }
}

// ---------------------------------------------------------------------------
// mfma_g: split-bf16 NT GEMM, 64(M) x 128(N) tile, BK=32, 4 waves
// (2 m-halves x 2 n-halves). 3-term: Ah*Bh + Ah*Bl + Al*Bh.
// ABF32: A is fp32 (converted in staging); else A is pre-split planes.
// NFAST: consecutive swizzled blocks share the m-panel (A-local);
// else share the n-panel (B-local). T1 bijective XCD-chunk swizzle (m204).
// Optional split-plane C outputs (Chi/Clo) for downstream bf16-A GEMMs.
// M must be a multiple of 64. N may be ragged.
// ---------------------------------------------------------------------------
template<bool ABF32, bool NFAST>
__global__ __launch_bounds__(256) void mfma_g(
    const float* __restrict__ A,
    const ushort* __restrict__ Ahi, const ushort* __restrict__ Alo,
    const ushort* __restrict__ Bhi, const ushort* __restrict__ Blo,
    const float* __restrict__ bias, float* __restrict__ C,
    ushort* __restrict__ Chi, ushort* __restrict__ Clo,
    int N, int K, int ldc, int NXB, int NMB)
{
    __shared__ __align__(16) ushort sAh[4][64][8];
    __shared__ __align__(16) ushort sAl[4][64][8];
    __shared__ __align__(16) ushort sBh[4][128][8];
    __shared__ __align__(16) ushort sBl[4][128][8];

    const int tid = threadIdx.x;

    // XCD-chunked bijective swizzle
    const int nwg = NXB * NMB;
    const int q = nwg >> 3, r = nwg & 7;
    const int xcd = blockIdx.x & 7, sidx = blockIdx.x >> 3;
    const int wg = (xcd < r) ? (xcd * (q + 1) + sidx)
                             : (r * (q + 1) + (xcd - r) * q + sidx);
    int im, inb;
    if (NFAST) { inb = wg % NXB; im = wg / NXB; }
    else       { im = wg % NMB; inb = wg / NMB; }
    const int m0 = im * 64;
    const int n0 = inb * 128;

    const int lane = tid & 63;
    const int w = tid >> 6;
    const int mh = (w & 1) * 32;
    const int nh = (w >> 1) * 64;
    const int g = lane >> 4, l15 = lane & 15;

    f32x4 acc[2][4] = {};

    for (int k0 = 0; k0 < K; k0 += 32) {
        __syncthreads();
        if (ABF32) {
            // 256 chunks: r_=tid>>2 (row), g_=tid&3 (k-group)
            int r_ = tid >> 2, g_ = tid & 3;
            const float* ap = A + (size_t)(m0 + r_) * K + k0 + g_ * 8;
            float av[8];
            *(float4*)(av)     = *(const float4*)(ap);
            *(float4*)(av + 4) = *(const float4*)(ap + 4);
            bfrag vh, vl;
            #pragma unroll
            for (int j = 0; j < 8; ++j) {
                ushort h = f2bf_rne(av[j]);
                vh[j] = (short)h;
                vl[j] = (short)f2bf_rne(av[j] - bf2f(h));
            }
            *(bfrag*)&sAh[g_][r_][0] = vh;
            *(bfrag*)&sAl[g_][r_][0] = vl;
        } else {
            #pragma unroll
            for (int i = 0; i < 2; ++i) {
                int c = tid + i * 256;
                int pl = c >> 8, idx2 = c & 255;
                int r_ = idx2 >> 2, g_ = idx2 & 3;
                const ushort* src = (pl ? Alo : Ahi) + (size_t)(m0 + r_) * K + k0 + g_ * 8;
                if (pl) *(bfrag*)&sAl[g_][r_][0] = *(const bfrag*)src;
                else    *(bfrag*)&sAh[g_][r_][0] = *(const bfrag*)src;
            }
        }
        #pragma unroll
        for (int i = 0; i < 4; ++i) {
            int c = tid + i * 256;
            int pl = c >> 9, idx2 = c & 511;
            int r_ = idx2 >> 2, g_ = idx2 & 3;
            int brow = min(n0 + r_, N - 1);
            const ushort* src = (pl ? Blo : Bhi) + (size_t)brow * K + k0 + g_ * 8;
            if (pl) *(bfrag*)&sBl[g_][r_][0] = *(const bfrag*)src;
            else    *(bfrag*)&sBh[g_][r_][0] = *(const bfrag*)src;
        }
        __syncthreads();

        bfrag ah[2], al[2], bh[4], bl[4];
        #pragma unroll
        for (int s = 0; s < 2; ++s) {
            ah[s] = *(const bfrag*)&sAh[g][mh + s * 16 + l15][0];
            al[s] = *(const bfrag*)&sAl[g][mh + s * 16 + l15][0];
        }
        #pragma unroll
        for (int u = 0; u < 4; ++u) {
            bh[u] = *(const bfrag*)&sBh[g][nh + u * 16 + l15][0];
            bl[u] = *(const bfrag*)&sBl[g][nh + u * 16 + l15][0];
        }
        #pragma unroll
        for (int s = 0; s < 2; ++s)
            #pragma unroll
            for (int u = 0; u < 4; ++u) {
                acc[s][u] = __builtin_amdgcn_mfma_f32_16x16x32_bf16(ah[s], bh[u], acc[s][u], 0, 0, 0);
                acc[s][u] = __builtin_amdgcn_mfma_f32_16x16x32_bf16(ah[s], bl[u], acc[s][u], 0, 0, 0);
                acc[s][u] = __builtin_amdgcn_mfma_f32_16x16x32_bf16(al[s], bh[u], acc[s][u], 0, 0, 0);
            }
    }

    #pragma unroll
    for (int s = 0; s < 2; ++s)
        #pragma unroll
        for (int u = 0; u < 4; ++u) {
            int col = n0 + nh + u * 16 + l15;
            if (col < N) {
                float bv = bias[col];
                #pragma unroll
                for (int rr = 0; rr < 4; ++rr) {
                    int row = m0 + mh + s * 16 + g * 4 + rr;
                    float v = acc[s][u][rr] + bv;
                    C[(size_t)row * ldc + col] = v;
                    if (Chi) {
                        ushort hh = f2bf_rne(v);
                        Chi[(size_t)row * ldc + col] = hh;
                        Clo[(size_t)row * ldc + col] = f2bf_rne(v - bf2f(hh));
                    }
                }
            }
        }
}

// ---------------------------------------------------------------------------
__global__ __launch_bounds__(256) void k_fmean(const float* __restrict__ f,
                                               float* __restrict__ fmean)
{
    int b = blockIdx.x, tid = threadIdx.x;
    for (int e = tid; e < EMB; e += 256) {
        const float* fb = f + (size_t)b * HW * EMB + e;
        float s = 0.f;
        for (int h = 0; h < HW; ++h) s += fb[(size_t)h * EMB];
        fmean[b * EMB + e] = s * (1.0f / HW);
    }
}

__global__ __launch_bounds__(256) void k_init(
    const float* __restrict__ fmean,
    const float* __restrict__ W_hi, const float* __restrict__ b_hi,
    const float* __restrict__ W_ci, const float* __restrict__ b_ci,
    float* __restrict__ hx, float* __restrict__ cx)
{
    int b = blockIdx.x, tid = threadIdx.x;
    __shared__ float fm[EMB];
    for (int i = tid; i < EMB; i += 256) fm[i] = fmean[b * EMB + i];
    __syncthreads();
    for (int u = tid; u < HID; u += 256) {
        const float4* w1 = (const float4*)(W_hi + (size_t)u * EMB);
        const float4* w2 = (const float4*)(W_ci + (size_t)u * EMB);
        float a1 = b_hi[u], a2 = b_ci[u];
        for (int k = 0; k < EMB / 4; ++k) {
            float4 y1 = w1[k], y2 = w2[k];
            float x0 = fm[4*k], x1 = fm[4*k+1], x2 = fm[4*k+2], x3 = fm[4*k+3];
            a1 += x0*y1.x + x1*y1.y + x2*y1.z + x3*y1.w;
            a2 += x0*y2.x + x1*y2.y + x2*y2.z + x3*y2.w;
        }
        hx[b * HID + u] = a1;
        cx[b * HID + u] = a2;
    }
}

// xs_hi/lo[t*64+b][:] = split(E[captions[b][t]][:])
__global__ __launch_bounds__(128) void k_embed_split(
    const int* __restrict__ cap, const float* __restrict__ E,
    ushort* __restrict__ xs_hi, ushort* __restrict__ xs_lo)
{
    int blk = blockIdx.x;
    int t = blk / BB, b = blk % BB;
    int c = cap[b * TT + t];
    float4 v = ((const float4*)(E + (size_t)c * EMB))[threadIdx.x];
    float av[4] = {v.x, v.y, v.z, v.w};
    ushort h[4], l[4];
    #pragma unroll
    for (int j = 0; j < 4; ++j) {
        h[j] = f2bf_rne(av[j]);
        l[j] = f2bf_rne(av[j] - bf2f(h[j]));
    }
    size_t base = ((size_t)t * BB + b) * EMB + threadIdx.x * 4;
    *(ushort4*)(xs_hi + base) = make_ushort4(h[0], h[1], h[2], h[3]);
    *(ushort4*)(xs_lo + base) = make_ushort4(l[0], l[1], l[2], l[3]);
}

// ---------------------------------------------------------------------------
// k_ha: ha[b][a] = hx[b].W2[a] + b2[a].  grid 256: block -> 16 a's x 8 b's.
// ---------------------------------------------------------------------------
__global__ __launch_bounds__(256) void k_ha(
    const float* __restrict__ hx, const float* __restrict__ W2,
    const float* __restrict__ b2, float* __restrict__ ha)
{
    __shared__ __align__(16) float hx_s[8][1028];
    __shared__ float part[256];
    const int tid = threadIdx.x;
    const int a0 = (blockIdx.x >> 3) * 16;
    const int b0 = (blockIdx.x & 7) * 8;

    for (int i = tid; i < 8 * 256; i += 256) {
        int r = i >> 8, c4 = i & 255;
        *(float4*)&hx_s[r][c4 * 4] = *(const float4*)(hx + (size_t)(b0 + r) * HID + c4 * 4);
    }
    __syncthreads();

    const int a_i = tid >> 4;
    const int b_i = (tid >> 1) & 7;
    const int half = tid & 1;
    const float4* wr = (const float4*)(W2 + (size_t)(a0 + a_i) * HID + half * 512);
    const float* xr = &hx_s[b_i][half * 512];
    float s = 0.f;
    #pragma unroll 8
    for (int i = 0; i < 128; ++i) {
        float4 w = wr[i];
        float4 x = *(const float4*)(xr + i * 4);
        s += w.x*x.x + w.y*x.y + w.z*x.z + w.w*x.w;
    }
    part[tid] = s;
    __syncthreads();
    if (!half)
        ha[(size_t)(b0 + b_i) * ATT + a0 + a_i] = part[tid] + part[tid + 1] + b2[a0 + a_i];
}

// ---------------------------------------------------------------------------
// k_att: one block per b (64 x 1024): logits (fa + ha precomputed) ->
// softmax -> ctx -> split planes. bV omitted (softmax-invariant).
// ---------------------------------------------------------------------------
__global__ __launch_bounds__(1024) void k_att(
    const float* __restrict__ f, const float* __restrict__ fa,
    const float* __restrict__ ha, const float* __restrict__ V,
    ushort* __restrict__ ctx_hi, ushort* __restrict__ ctx_lo)
{
    __shared__ __align__(16) float smem[2048];
    const int b = blockIdx.x;
    const int tid = threadIdx.x;
    const int lane = tid & 63;
    const int wid = tid >> 6;

    float* ha_s = smem;          // 512
    float* V_s  = smem + 512;    // 512
    float* w_s  = smem + 1024;   // 256 (196 used)
    float* red  = smem + 1280;   // 256
    float* pc   = smem + 1536;   // 512

    if (tid < ATT) { ha_s[tid] = ha[b * ATT + tid]; V_s[tid] = V[tid]; }
    __syncthreads();

    for (int h = wid; h < HW; h += 16) {
        const float4* fr = (const float4*)(fa + ((size_t)b * HW + h) * ATT);
        float s = 0.f;
        #pragma unroll
        for (int q = 0; q < 2; ++q) {
            int i4 = q * 64 + lane;
            float4 fv = fr[i4];
            float4 hv = *(const float4*)&ha_s[i4 * 4];
            float4 vv = *(const float4*)&V_s[i4 * 4];
            s += tanh_fast(fv.x + hv.x) * vv.x + tanh_fast(fv.y + hv.y) * vv.y
               + tanh_fast(fv.z + hv.z) * vv.z + tanh_fast(fv.w + hv.w) * vv.w;
        }
        #pragma unroll
        for (int off = 32; off > 0; off >>= 1) s += __shfl_down(s, off);
        if (lane == 0) w_s[h] = s;
    }
    __syncthreads();

    float v = (tid < HW) ? w_s[tid] : -INFINITY;
    if (tid < 256) red[tid] = v;
    __syncthreads();
    for (int s2 = 128; s2 > 0; s2 >>= 1) {
        if (tid < s2) red[tid] = fmaxf(red[tid], red[tid + s2]);
        __syncthreads();
    }
    float mx = red[0];
    __syncthreads();
    float e = (tid < HW) ? __expf(v - mx) : 0.f;
    if (tid < 256) red[tid] = e;
    __syncthreads();
    for (int s2 = 128; s2 > 0; s2 >>= 1) {
        if (tid < s2) red[tid] += red[tid + s2];
        __syncthreads();
    }
    float inv = 1.0f / red[0];
    if (tid < HW) w_s[tid] = e * inv;
    __syncthreads();

    {
        int e0 = tid & 511, grp = tid >> 9;
        const float* fb = f + (size_t)b * HW * EMB + e0;
        float s = 0.f;
        int h0 = grp * 98;
        for (int h = h0; h < h0 + 98; ++h)
            s = fmaf(w_s[h], fb[(size_t)h * EMB], s);
        if (grp) pc[e0] = s;
        __syncthreads();
        if (!grp) {
            float c = s + pc[e0];
            ushort ch = f2bf_rne(c);
            ctx_hi[b * EMB + e0] = ch;
            ctx_lo[b * EMB + e0] = f2bf_rne(c - bf2f(ch));
        }
    }
}

// ---------------------------------------------------------------------------
// k_gates_lstm: gates GEMM (split-bf16 MFMA, operands direct from L2/L3)
// + fused LSTM. grid 256 x 256 thr. Block bk owns u in [bk*4, bk*4+4) for
// ALL 4 gates: ncol(l15) = (l15>>2)*1024 + bk*4 + (l15&3). 4 waves = 4
// m-tiles of 16 batch rows. Epilogue: 4KB LDS gate exchange -> LSTM ->
// hx fp32, cx, hx planes (PARITY double-buffered: fused kernel would race
// single-buffered), hx_all fp32 + planes (vocab GEMM A).
// ---------------------------------------------------------------------------
__global__ __launch_bounds__(256) void k_gates_lstm(
    const ushort* __restrict__ xsh, const ushort* __restrict__ xsl,   // [64][512]
    const ushort* __restrict__ cth, const ushort* __restrict__ ctl,   // [64][512]
    const ushort* __restrict__ hxh, const ushort* __restrict__ hxl,   // [64][1024] read
    const ushort* __restrict__ wihh, const ushort* __restrict__ wihl, // [4096][1024]
    const ushort* __restrict__ whhh, const ushort* __restrict__ whhl, // [4096][1024]
    const float* __restrict__ b_ih, const float* __restrict__ b_hh,
    float* __restrict__ hx, float* __restrict__ cx,
    ushort* __restrict__ nxh, ushort* __restrict__ nxl,               // write planes
    float* __restrict__ hx_all_t,
    ushort* __restrict__ hxa_h, ushort* __restrict__ hxa_l)           // hx_all planes row t*64
{
    __shared__ float sg[64][16];   // 4 KB
    const int tid = threadIdx.x, bk = blockIdx.x;
    const int lane = tid & 63, mt = tid >> 6;
    const int l15 = lane & 15, g = lane >> 4;
    const int arow = mt * 16 + l15;
    const int ncol = (l15 >> 2) * 1024 + bk * 4 + (l15 & 3);
    const int koff = g * 8;

    f32x4 acc0 = {}, acc1 = {};

    {   // seg 0: xs . W_ih[:, 0:512)
        const ushort* ah = xsh + (size_t)arow * 512 + koff;
        const ushort* al = xsl + (size_t)arow * 512 + koff;
        const ushort* bh = wihh + (size_t)ncol * 1024 + koff;
        const ushort* bl = wihl + (size_t)ncol * 1024 + koff;
        #pragma unroll 4
        for (int kk = 0; kk < 16; ++kk) {
            bfrag a_h = *(const bfrag*)(ah + kk * 32);
            bfrag a_l = *(const bfrag*)(al + kk * 32);
            bfrag b_h = *(const bfrag*)(bh + kk * 32);
            bfrag b_l = *(const bfrag*)(bl + kk * 32);
            acc0 = __builtin_amdgcn_mfma_f32_16x16x32_bf16(a_h, b_h, acc0, 0, 0, 0);
            acc1 = __builtin_amdgcn_mfma_f32_16x16x32_bf16(a_h, b_l, acc1, 0, 0, 0);
            acc1 = __builtin_amdgcn_mfma_f32_16x16x32_bf16(a_l, b_h, acc1, 0, 0, 0);
        }
    }
    {   // seg 1: ctx . W_ih[:, 512:1024)
        const ushort* ah = cth + (size_t)arow * 512 + koff;
        const ushort* al = ctl + (size_t)arow * 512 + koff;
        const ushort* bh = wihh + (size_t)ncol * 1024 + 512 + koff;
        const ushort* bl = wihl + (size_t)ncol * 1024 + 512 + koff;
        #pragma unroll 4
        for (int kk = 0; kk < 16; ++kk) {
            bfrag a_h = *(const bfrag*)(ah + kk * 32);
            bfrag a_l = *(const bfrag*)(al + kk * 32);
            bfrag b_h = *(const bfrag*)(bh + kk * 32);
            bfrag b_l = *(const bfrag*)(bl + kk * 32);
            acc0 = __builtin_amdgcn_mfma_f32_16x16x32_bf16(a_h, b_h, acc0, 0, 0, 0);
            acc1 = __builtin_amdgcn_mfma_f32_16x16x32_bf16(a_h, b_l, acc1, 0, 0, 0);
            acc1 = __builtin_amdgcn_mfma_f32_16x16x32_bf16(a_l, b_h, acc1, 0, 0, 0);
        }
    }
    {   // seg 2: hx . W_hh
        const ushort* ah = hxh + (size_t)arow * 1024 + koff;
        const ushort* al = hxl + (size_t)arow * 1024 + koff;
        const ushort* bh = whhh + (size_t)ncol * 1024 + koff;
        const ushort* bl = whhl + (size_t)ncol * 1024 + koff;
        #pragma unroll 4
        for (int kk = 0; kk < 32; ++kk) {
            bfrag a_h = *(const bfrag*)(ah + kk * 32);
            bfrag a_l = *(const bfrag*)(al + kk * 32);
            bfrag b_h = *(const bfrag*)(bh + kk * 32);
            bfrag b_l = *(const bfrag*)(bl + kk * 32);
            acc0 = __builtin_amdgcn_mfma_f32_16x16x32_bf16(a_h, b_h, acc0, 0, 0, 0);
            acc1 = __builtin_amdgcn_mfma_f32_16x16x32_bf16(a_h, b_l, acc1, 0, 0, 0);
            acc1 = __builtin_amdgcn_mfma_f32_16x16x32_bf16(a_l, b_h, acc1, 0, 0, 0);
        }
    }

    #pragma unroll
    for (int rr = 0; rr < 4; ++rr)
        sg[mt * 16 + g * 4 + rr][l15] = acc0[rr] + acc1[rr];
    __syncthreads();

    {
        int b = tid >> 2, uu = tid & 3;
        int u = bk * 4 + uu;
        float gi = sg[b][uu]      + b_ih[u]        + b_hh[u];
        float gf = sg[b][4 + uu]  + b_ih[1024 + u] + b_hh[1024 + u];
        float gg = sg[b][8 + uu]  + b_ih[2048 + u] + b_hh[2048 + u];
        float go = sg[b][12 + uu] + b_ih[3072 + u] + b_hh[3072 + u];
        int idx = b * 1024 + u;
        float c = sigmoid_fast(gf) * cx[idx] + sigmoid_fast(gi) * tanh_fast(gg);
        float h = sigmoid_fast(go) * tanh_fast(c);
        cx[idx] = c;
        hx[idx] = h;
        hx_all_t[idx] = h;
        ushort hh = f2bf_rne(h);
        ushort hl = f2bf_rne(h - bf2f(hh));
        nxh[idx] = hh; nxl[idx] = hl;
        hxa_h[idx] = hh; hxa_l[idx] = hl;
    }
}

// ---------------------------------------------------------------------------
extern "C" void kernel_launch(void* const* d_in, const int* in_sizes, int n_in,
                              void* d_out, int out_size, void* d_ws, size_t ws_size,
                              hipStream_t stream) {
    const float* features = (const float*)d_in[0];
    const int*   captions = (const int*)d_in[1];
    const float* E      = (const float*)d_in[3];
    const float* W_feat = (const float*)d_in[4];
    const float* b_feat = (const float*)d_in[5];
    const float* W1     = (const float*)d_in[6];
    const float* b1     = (const float*)d_in[7];
    const float* W2     = (const float*)d_in[8];
    const float* b2     = (const float*)d_in[9];
    const float* V      = (const float*)d_in[10];
    // d_in[11] bV: softmax-invariant, unused
    const float* W_hi   = (const float*)d_in[12];
    const float* b_hi   = (const float*)d_in[13];
    const float* W_ci   = (const float*)d_in[14];
    const float* b_ci   = (const float*)d_in[15];
    const float* W_ih   = (const float*)d_in[16];
    const float* b_ih   = (const float*)d_in[17];
    const float* W_hh   = (const float*)d_in[18];
    const float* b_hh   = (const float*)d_in[19];
    const float* W_out  = (const float*)d_in[20];
    const float* b_out  = (const float*)d_in[21];
    float* out = (float*)d_out;

    // ---- workspace layout ----
    float* ws = (float*)d_ws;
    float* f_buf   = ws;                          // 6,422,528
    float* fa_buf  = f_buf + 6422528;             // 6,422,528
    float* fmean   = fa_buf + 6422528;            // 32,768
    float* hx      = fmean + 32768;               // 65,536
    float* cx      = hx + 65536;                  // 65,536
    float* hx_all  = cx + 65536;                  // 1,310,720
    float* ha      = hx_all + 1310720;            // 32,768
    ushort* p = (ushort*)(ha + 32768);
    ushort* f_hi     = p;            p += 6422528;
    ushort* f_lo     = p;            p += 6422528;
    ushort* wfeat_hi = p;            p += 1048576;
    ushort* wfeat_lo = p;            p += 1048576;
    ushort* w1_hi    = p;            p += 262144;
    ushort* w1_lo    = p;            p += 262144;
    ushort* wih_hi   = p;            p += 4194304;
    ushort* wih_lo   = p;            p += 4194304;
    ushort* whh_hi   = p;            p += 4194304;
    ushort* whh_lo   = p;            p += 4194304;
    ushort* xs_hi    = p;            p += 622592;
    ushort* xs_lo    = p;            p += 622592;
    ushort* ctx_hi   = p;            p += 32768;
    ushort* ctx_lo   = p;            p += 32768;
    ushort* hxp      = p;            p += 262144;   // [2 bufs][hi|lo][65536]
    ushort* hxa_hi   = p;            p += 1310720;
    ushort* hxa_lo   = p;            p += 1310720;
    // W_out planes reuse f_buf+fa_buf region after the step loop (41MB <= 51MB)
    ushort* wout_hi = (ushort*)f_buf;
    ushort* wout_lo = wout_hi + 10240000;

    // ---- precompute ----
    k_split<<<1048576 / 4 / 256, 256, 0, stream>>>(W_feat, wfeat_hi, wfeat_lo, 1048576);
    k_split<<<262144 / 4 / 256, 256, 0, stream>>>(W1, w1_hi, w1_lo, 262144);
    k_split<<<4194304 / 4 / 256, 256, 0, stream>>>(W_ih, wih_hi, wih_lo, 4194304);
    k_split<<<4194304 / 4 / 256, 256, 0, stream>>>(W_hh, whh_hi, whh_lo, 4194304);
    // f = features @ W_feat^T + b_feat  [12544,512], K=2048 (+ planes for fa)
    mfma_g<true, true><<<784, 256, 0, stream>>>(
        features, nullptr, nullptr, wfeat_hi, wfeat_lo, b_feat,
        f_buf, f_hi, f_lo, 512, 2048, 512, 4, 196);
    // fa = f @ W1^T + b1  [12544,512], K=512 (bf16-A)
    mfma_g<false, true><<<784, 256, 0, stream>>>(
        nullptr, f_hi, f_lo, w1_hi, w1_lo, b1,
        fa_buf, nullptr, nullptr, 512, 512, 512, 4, 196);
    k_fmean<<<BB, 256, 0, stream>>>(f_buf, fmean);
    k_init<<<BB, 256, 0, stream>>>(fmean, W_hi, b_hi, W_ci, b_ci, hx, cx);
    k_split<<<65536 / 4 / 256, 256, 0, stream>>>(hx, hxp, hxp + 65536, 65536);
    k_embed_split<<<STEPS * BB, 128, 0, stream>>>(captions, E, xs_hi, xs_lo);

    // ---- recurrent steps: 3 dispatches per step ----
    for (int t = 0; t < STEPS; ++t) {
        ushort* hx_rd = hxp + (size_t)(t & 1) * 131072;
        ushort* hx_wr = hxp + (size_t)((t + 1) & 1) * 131072;
        k_ha<<<256, 256, 0, stream>>>(hx, W2, b2, ha);
        k_att<<<BB, 1024, 0, stream>>>(f_buf, fa_buf, ha, V, ctx_hi, ctx_lo);
        k_gates_lstm<<<256, 256, 0, stream>>>(
            xs_hi + (size_t)t * BB * EMB, xs_lo + (size_t)t * BB * EMB,
            ctx_hi, ctx_lo, hx_rd, hx_rd + 65536,
            wih_hi, wih_lo, whh_hi, whh_lo, b_ih, b_hh,
            hx, cx, hx_wr, hx_wr + 65536,
            hx_all + (size_t)t * BB * HID,
            hxa_hi + (size_t)t * BB * HID, hxa_lo + (size_t)t * BB * HID);
    }

    // ---- vocab projection over all steps: [1216,10000], K=1024 (bf16-A) ----
    k_split<<<10240000 / 4 / 256, 256, 0, stream>>>(W_out, wout_hi, wout_lo, 10240000);
    mfma_g<false, false><<<1501, 256, 0, stream>>>(
        nullptr, hxa_hi, hxa_lo, wout_hi, wout_lo, b_out,
        out, nullptr, nullptr, VOCAB, HID, VOCAB, 79, 19);
}

// Round 9
// 1797.727 us; speedup vs baseline: 4.5300x; 1.0494x over previous
//
#include <hip/hip_runtime.h>
#include <hip/hip_bf16.h>
#include <math.h>

#define BB 64
#define HW 196
#define FEAT 2048
#define EMB 512
#define HID 1024
#define ATT 512
#define VOCAB 10000
#define TT 20
#define STEPS 19

using bfrag = __attribute__((ext_vector_type(8))) short;   // 8 bf16 = 4 VGPR
using f32x4 = __attribute__((ext_vector_type(4))) float;

__device__ __forceinline__ float sigmoid_fast(float x) { return 1.0f / (1.0f + __expf(-x)); }
__device__ __forceinline__ float tanh_fast(float x) {
    float e = __expf(2.0f * x);
    return 1.0f - 2.0f / (e + 1.0f);
}
__device__ __forceinline__ ushort f2bf_rne(float f) {
    unsigned u = __float_as_uint(f);
    unsigned r = (u + 0x7FFFu + ((u >> 16) & 1u)) >> 16;
    return (ushort)r;
}
__device__ __forceinline__ float bf2f(ushort h) {
    return __uint_as_float(((unsigned)h) << 16);
}
// XOR bank swizzle for 16B LDS chunks: row-major 4 chunks/row, g permuted by row.
__device__ __forceinline__ int sw_idx(int row, int g) { return row * 4 + (g ^ (row & 3)); }

// ---------------------------------------------------------------------------
// fp32 -> split bf16 planes: x = hi + lo.  n % 1024 == 0.
// ---------------------------------------------------------------------------
__global__ __launch_bounds__(256) void k_split(const float* __restrict__ x,
                                               ushort* __restrict__ hi,
                                               ushort* __restrict__ lo, int n)
{
    int i4 = (blockIdx.x * 256 + threadIdx.x) * 4;
    if (i4 >= n) return;
    float4 v = *(const float4*)(x + i4);
    float av[4] = {v.x, v.y, v.z, v.w};
    #pragma unroll
    for (int j = 0; j < 4; ++j) {
        ushort h = f2bf_rne(av[j]);
        hi[i4 + j] = h;
        lo[i4 + j] = f2bf_rne(av[j] - bf2f(h));
    }
}

// ---------------------------------------------------------------------------
// mfma_g: split-bf16 NT GEMM, 64(M) x 128(N) tile, BK=32, 4 waves
// (2 m-halves x 2 n-halves). 3-term: Ah*Bh + Ah*Bl + Al*Bh.
// A fp32 (split during staging); B pre-split planes. LDS XOR-swizzled
// (sw_idx) so fragment ds_read_b128 is conflict-free (2-way only).
// NFAST: consecutive swizzled blocks share the m-panel; else n-panel.
// T1 bijective XCD-chunk swizzle. M multiple of 64; N ragged OK.
// ---------------------------------------------------------------------------
template<bool NFAST>
__global__ __launch_bounds__(256) void mfma_g(
    const float* __restrict__ A,
    const ushort* __restrict__ Bhi, const ushort* __restrict__ Blo,
    const float* __restrict__ bias, float* __restrict__ C,
    int N, int K, int ldc, int NXB, int NMB)
{
    __shared__ __align__(16) ushort sAh[256 * 8];
    __shared__ __align__(16) ushort sAl[256 * 8];
    __shared__ __align__(16) ushort sBh[512 * 8];
    __shared__ __align__(16) ushort sBl[512 * 8];

    const int tid = threadIdx.x;

    // XCD-chunked bijective swizzle
    const int nwg = NXB * NMB;
    const int q = nwg >> 3, r = nwg & 7;
    const int xcd = blockIdx.x & 7, sidx = blockIdx.x >> 3;
    const int wg = (xcd < r) ? (xcd * (q + 1) + sidx)
                             : (r * (q + 1) + (xcd - r) * q + sidx);
    int im, inb;
    if (NFAST) { inb = wg % NXB; im = wg / NXB; }
    else       { im = wg % NMB; inb = wg / NMB; }
    const int m0 = im * 64;
    const int n0 = inb * 128;

    const int lane = tid & 63;
    const int w = tid >> 6;
    const int mh = (w & 1) * 32;
    const int nh = (w >> 1) * 64;
    const int g = lane >> 4, l15 = lane & 15;

    f32x4 acc[2][4] = {};

    for (int k0 = 0; k0 < K; k0 += 32) {
        __syncthreads();
        {   // A: fp32 -> hi/lo, swizzled store
            int r_ = tid >> 2, g_ = tid & 3;
            const float* ap = A + (size_t)(m0 + r_) * K + k0 + g_ * 8;
            float av[8];
            *(float4*)(av)     = *(const float4*)(ap);
            *(float4*)(av + 4) = *(const float4*)(ap + 4);
            bfrag vh, vl;
            #pragma unroll
            for (int j = 0; j < 8; ++j) {
                ushort h = f2bf_rne(av[j]);
                vh[j] = (short)h;
                vl[j] = (short)f2bf_rne(av[j] - bf2f(h));
            }
            int c = sw_idx(r_, g_) * 8;
            *(bfrag*)&sAh[c] = vh;
            *(bfrag*)&sAl[c] = vl;
        }
        #pragma unroll
        for (int i = 0; i < 4; ++i) {   // B planes, swizzled store
            int c = tid + i * 256;
            int pl = c >> 9, idx2 = c & 511;
            int r_ = idx2 >> 2, g_ = idx2 & 3;
            int brow = min(n0 + r_, N - 1);
            const ushort* src = (pl ? Blo : Bhi) + (size_t)brow * K + k0 + g_ * 8;
            int cc = sw_idx(r_, g_) * 8;
            if (pl) *(bfrag*)&sBl[cc] = *(const bfrag*)src;
            else    *(bfrag*)&sBh[cc] = *(const bfrag*)src;
        }
        __syncthreads();

        bfrag ah[2], al[2], bh[4], bl[4];
        #pragma unroll
        for (int s = 0; s < 2; ++s) {
            int c = sw_idx(mh + s * 16 + l15, g) * 8;
            ah[s] = *(const bfrag*)&sAh[c];
            al[s] = *(const bfrag*)&sAl[c];
        }
        #pragma unroll
        for (int u = 0; u < 4; ++u) {
            int c = sw_idx(nh + u * 16 + l15, g) * 8;
            bh[u] = *(const bfrag*)&sBh[c];
            bl[u] = *(const bfrag*)&sBl[c];
        }
        #pragma unroll
        for (int s = 0; s < 2; ++s)
            #pragma unroll
            for (int u = 0; u < 4; ++u) {
                acc[s][u] = __builtin_amdgcn_mfma_f32_16x16x32_bf16(ah[s], bh[u], acc[s][u], 0, 0, 0);
                acc[s][u] = __builtin_amdgcn_mfma_f32_16x16x32_bf16(ah[s], bl[u], acc[s][u], 0, 0, 0);
                acc[s][u] = __builtin_amdgcn_mfma_f32_16x16x32_bf16(al[s], bh[u], acc[s][u], 0, 0, 0);
            }
    }

    #pragma unroll
    for (int s = 0; s < 2; ++s)
        #pragma unroll
        for (int u = 0; u < 4; ++u) {
            int col = n0 + nh + u * 16 + l15;
            if (col < N) {
                float bv = bias[col];
                #pragma unroll
                for (int rr = 0; rr < 4; ++rr) {
                    int row = m0 + mh + s * 16 + g * 4 + rr;
                    C[(size_t)row * ldc + col] = acc[s][u][rr] + bv;
                }
            }
        }
}

// ---------------------------------------------------------------------------
__global__ __launch_bounds__(256) void k_fmean(const float* __restrict__ f,
                                               float* __restrict__ fmean)
{
    int b = blockIdx.x, tid = threadIdx.x;
    for (int e = tid; e < EMB; e += 256) {
        const float* fb = f + (size_t)b * HW * EMB + e;
        float s = 0.f;
        for (int h = 0; h < HW; ++h) s += fb[(size_t)h * EMB];
        fmean[b * EMB + e] = s * (1.0f / HW);
    }
}

__global__ __launch_bounds__(256) void k_init(
    const float* __restrict__ fmean,
    const float* __restrict__ W_hi, const float* __restrict__ b_hi,
    const float* __restrict__ W_ci, const float* __restrict__ b_ci,
    float* __restrict__ hx, float* __restrict__ cx)
{
    int b = blockIdx.x, tid = threadIdx.x;
    __shared__ float fm[EMB];
    for (int i = tid; i < EMB; i += 256) fm[i] = fmean[b * EMB + i];
    __syncthreads();
    for (int u = tid; u < HID; u += 256) {
        const float4* w1 = (const float4*)(W_hi + (size_t)u * EMB);
        const float4* w2 = (const float4*)(W_ci + (size_t)u * EMB);
        float a1 = b_hi[u], a2 = b_ci[u];
        for (int k = 0; k < EMB / 4; ++k) {
            float4 y1 = w1[k], y2 = w2[k];
            float x0 = fm[4*k], x1 = fm[4*k+1], x2 = fm[4*k+2], x3 = fm[4*k+3];
            a1 += x0*y1.x + x1*y1.y + x2*y1.z + x3*y1.w;
            a2 += x0*y2.x + x1*y2.y + x2*y2.z + x3*y2.w;
        }
        hx[b * HID + u] = a1;
        cx[b * HID + u] = a2;
    }
}

// xs_hi/lo[t*64+b][:] = split(E[captions[b][t]][:])
__global__ __launch_bounds__(128) void k_embed_split(
    const int* __restrict__ cap, const float* __restrict__ E,
    ushort* __restrict__ xs_hi, ushort* __restrict__ xs_lo)
{
    int blk = blockIdx.x;
    int t = blk / BB, b = blk % BB;
    int c = cap[b * TT + t];
    float4 v = ((const float4*)(E + (size_t)c * EMB))[threadIdx.x];
    float av[4] = {v.x, v.y, v.z, v.w};
    ushort h[4], l[4];
    #pragma unroll
    for (int j = 0; j < 4; ++j) {
        h[j] = f2bf_rne(av[j]);
        l[j] = f2bf_rne(av[j] - bf2f(h[j]));
    }
    size_t base = ((size_t)t * BB + b) * EMB + threadIdx.x * 4;
    *(ushort4*)(xs_hi + base) = make_ushort4(h[0], h[1], h[2], h[3]);
    *(ushort4*)(xs_lo + base) = make_ushort4(l[0], l[1], l[2], l[3]);
}

// ---------------------------------------------------------------------------
// k_ha: ha[b][a] = hx[b].W2[a] + b2[a].  grid 256: block -> 16 a's x 8 b's.
// ---------------------------------------------------------------------------
__global__ __launch_bounds__(256) void k_ha(
    const float* __restrict__ hx, const float* __restrict__ W2,
    const float* __restrict__ b2, float* __restrict__ ha)
{
    __shared__ __align__(16) float hx_s[8][1028];
    __shared__ float part[256];
    const int tid = threadIdx.x;
    const int a0 = (blockIdx.x >> 3) * 16;
    const int b0 = (blockIdx.x & 7) * 8;

    for (int i = tid; i < 8 * 256; i += 256) {
        int r = i >> 8, c4 = i & 255;
        *(float4*)&hx_s[r][c4 * 4] = *(const float4*)(hx + (size_t)(b0 + r) * HID + c4 * 4);
    }
    __syncthreads();

    const int a_i = tid >> 4;
    const int b_i = (tid >> 1) & 7;
    const int half = tid & 1;
    const float4* wr = (const float4*)(W2 + (size_t)(a0 + a_i) * HID + half * 512);
    const float* xr = &hx_s[b_i][half * 512];
    float s = 0.f;
    #pragma unroll 8
    for (int i = 0; i < 128; ++i) {
        float4 w = wr[i];
        float4 x = *(const float4*)(xr + i * 4);
        s += w.x*x.x + w.y*x.y + w.z*x.z + w.w*x.w;
    }
    part[tid] = s;
    __syncthreads();
    if (!half)
        ha[(size_t)(b0 + b_i) * ATT + a0 + a_i] = part[tid] + part[tid + 1] + b2[a0 + a_i];
}

// ---------------------------------------------------------------------------
// k_att: one block per b (64 x 1024): logits -> softmax -> ctx -> planes.
// ---------------------------------------------------------------------------
__global__ __launch_bounds__(1024) void k_att(
    const float* __restrict__ f, const float* __restrict__ fa,
    const float* __restrict__ ha, const float* __restrict__ V,
    ushort* __restrict__ ctx_hi, ushort* __restrict__ ctx_lo)
{
    __shared__ __align__(16) float smem[2048];
    const int b = blockIdx.x;
    const int tid = threadIdx.x;
    const int lane = tid & 63;
    const int wid = tid >> 6;

    float* ha_s = smem;          // 512
    float* V_s  = smem + 512;    // 512
    float* w_s  = smem + 1024;   // 256 (196 used)
    float* red  = smem + 1280;   // 256
    float* pc   = smem + 1536;   // 512

    if (tid < ATT) { ha_s[tid] = ha[b * ATT + tid]; V_s[tid] = V[tid]; }
    __syncthreads();

    for (int h = wid; h < HW; h += 16) {
        const float4* fr = (const float4*)(fa + ((size_t)b * HW + h) * ATT);
        float s = 0.f;
        #pragma unroll
        for (int q = 0; q < 2; ++q) {
            int i4 = q * 64 + lane;
            float4 fv = fr[i4];
            float4 hv = *(const float4*)&ha_s[i4 * 4];
            float4 vv = *(const float4*)&V_s[i4 * 4];
            s += tanh_fast(fv.x + hv.x) * vv.x + tanh_fast(fv.y + hv.y) * vv.y
               + tanh_fast(fv.z + hv.z) * vv.z + tanh_fast(fv.w + hv.w) * vv.w;
        }
        #pragma unroll
        for (int off = 32; off > 0; off >>= 1) s += __shfl_down(s, off);
        if (lane == 0) w_s[h] = s;
    }
    __syncthreads();

    float v = (tid < HW) ? w_s[tid] : -INFINITY;
    if (tid < 256) red[tid] = v;
    __syncthreads();
    for (int s2 = 128; s2 > 0; s2 >>= 1) {
        if (tid < s2) red[tid] = fmaxf(red[tid], red[tid + s2]);
        __syncthreads();
    }
    float mx = red[0];
    __syncthreads();
    float e = (tid < HW) ? __expf(v - mx) : 0.f;
    if (tid < 256) red[tid] = e;
    __syncthreads();
    for (int s2 = 128; s2 > 0; s2 >>= 1) {
        if (tid < s2) red[tid] += red[tid + s2];
        __syncthreads();
    }
    float inv = 1.0f / red[0];
    if (tid < HW) w_s[tid] = e * inv;
    __syncthreads();

    {
        int e0 = tid & 511, grp = tid >> 9;
        const float* fb = f + (size_t)b * HW * EMB + e0;
        float s = 0.f;
        int h0 = grp * 98;
        for (int h = h0; h < h0 + 98; ++h)
            s = fmaf(w_s[h], fb[(size_t)h * EMB], s);
        if (grp) pc[e0] = s;
        __syncthreads();
        if (!grp) {
            float c = s + pc[e0];
            ushort ch = f2bf_rne(c);
            ctx_hi[b * EMB + e0] = ch;
            ctx_lo[b * EMB + e0] = f2bf_rne(c - bf2f(ch));
        }
    }
}

// ---------------------------------------------------------------------------
// k_gates_lstm: gates GEMM (split-bf16 MFMA, operands from L2/L3) + fused
// LSTM. grid 256 x 512 thr (8 waves = 2/SIMD for latency hiding).
// Wave (mt, kh): mt = m-tile (16 batch rows), kh = K-half:
//   kh0: xs(512) + ctx(512); kh1: hx(1024).
// ncol(l15) = (l15>>2)*1024 + bk*4 + (l15&3) -> block owns u in
// [bk*4,+4) for all 4 gates. Epilogue: 8KB LDS 2-partial reduce -> LSTM ->
// hx, cx, next hx planes (parity double-buffered), hx_all fp32.
// ---------------------------------------------------------------------------
__global__ __launch_bounds__(512) void k_gates_lstm(
    const ushort* __restrict__ xsh, const ushort* __restrict__ xsl,   // [64][512]
    const ushort* __restrict__ cth, const ushort* __restrict__ ctl,   // [64][512]
    const ushort* __restrict__ hxh, const ushort* __restrict__ hxl,   // [64][1024] read
    const ushort* __restrict__ wihh, const ushort* __restrict__ wihl, // [4096][1024]
    const ushort* __restrict__ whhh, const ushort* __restrict__ whhl, // [4096][1024]
    const float* __restrict__ b_ih, const float* __restrict__ b_hh,
    float* __restrict__ hx, float* __restrict__ cx,
    ushort* __restrict__ nxh, ushort* __restrict__ nxl,               // write planes
    float* __restrict__ hx_all_t)
{
    __shared__ float sg[2][64][16];   // 8 KB
    const int tid = threadIdx.x, bk = blockIdx.x;
    const int lane = tid & 63, wid = tid >> 6;
    const int mt = wid & 3, kh = wid >> 2;
    const int l15 = lane & 15, g = lane >> 4;
    const int arow = mt * 16 + l15;
    const int ncol = (l15 >> 2) * 1024 + bk * 4 + (l15 & 3);
    const int koff = g * 8;

    f32x4 acc0 = {}, acc1 = {};

    if (kh == 0) {
        {   // xs . W_ih[:, 0:512)
            const ushort* ah = xsh + (size_t)arow * 512 + koff;
            const ushort* al = xsl + (size_t)arow * 512 + koff;
            const ushort* bh = wihh + (size_t)ncol * 1024 + koff;
            const ushort* bl = wihl + (size_t)ncol * 1024 + koff;
            #pragma unroll 4
            for (int kk = 0; kk < 16; ++kk) {
                bfrag a_h = *(const bfrag*)(ah + kk * 32);
                bfrag a_l = *(const bfrag*)(al + kk * 32);
                bfrag b_h = *(const bfrag*)(bh + kk * 32);
                bfrag b_l = *(const bfrag*)(bl + kk * 32);
                acc0 = __builtin_amdgcn_mfma_f32_16x16x32_bf16(a_h, b_h, acc0, 0, 0, 0);
                acc1 = __builtin_amdgcn_mfma_f32_16x16x32_bf16(a_h, b_l, acc1, 0, 0, 0);
                acc1 = __builtin_amdgcn_mfma_f32_16x16x32_bf16(a_l, b_h, acc1, 0, 0, 0);
            }
        }
        {   // ctx . W_ih[:, 512:1024)
            const ushort* ah = cth + (size_t)arow * 512 + koff;
            const ushort* al = ctl + (size_t)arow * 512 + koff;
            const ushort* bh = wihh + (size_t)ncol * 1024 + 512 + koff;
            const ushort* bl = wihl + (size_t)ncol * 1024 + 512 + koff;
            #pragma unroll 4
            for (int kk = 0; kk < 16; ++kk) {
                bfrag a_h = *(const bfrag*)(ah + kk * 32);
                bfrag a_l = *(const bfrag*)(al + kk * 32);
                bfrag b_h = *(const bfrag*)(bh + kk * 32);
                bfrag b_l = *(const bfrag*)(bl + kk * 32);
                acc0 = __builtin_amdgcn_mfma_f32_16x16x32_bf16(a_h, b_h, acc0, 0, 0, 0);
                acc1 = __builtin_amdgcn_mfma_f32_16x16x32_bf16(a_h, b_l, acc1, 0, 0, 0);
                acc1 = __builtin_amdgcn_mfma_f32_16x16x32_bf16(a_l, b_h, acc1, 0, 0, 0);
            }
        }
    } else {
        // hx . W_hh
        const ushort* ah = hxh + (size_t)arow * 1024 + koff;
        const ushort* al = hxl + (size_t)arow * 1024 + koff;
        const ushort* bh = whhh + (size_t)ncol * 1024 + koff;
        const ushort* bl = whhl + (size_t)ncol * 1024 + koff;
        #pragma unroll 4
        for (int kk = 0; kk < 32; ++kk) {
            bfrag a_h = *(const bfrag*)(ah + kk * 32);
            bfrag a_l = *(const bfrag*)(al + kk * 32);
            bfrag b_h = *(const bfrag*)(bh + kk * 32);
            bfrag b_l = *(const bfrag*)(bl + kk * 32);
            acc0 = __builtin_amdgcn_mfma_f32_16x16x32_bf16(a_h, b_h, acc0, 0, 0, 0);
            acc1 = __builtin_amdgcn_mfma_f32_16x16x32_bf16(a_h, b_l, acc1, 0, 0, 0);
            acc1 = __builtin_amdgcn_mfma_f32_16x16x32_bf16(a_l, b_h, acc1, 0, 0, 0);
        }
    }

    #pragma unroll
    for (int rr = 0; rr < 4; ++rr)
        sg[kh][mt * 16 + g * 4 + rr][l15] = acc0[rr] + acc1[rr];
    __syncthreads();

    if (tid < 256) {
        int b = tid >> 2, uu = tid & 3;
        int u = bk * 4 + uu;
        float gi = sg[0][b][uu]      + sg[1][b][uu]      + b_ih[u]        + b_hh[u];
        float gf = sg[0][b][4 + uu]  + sg[1][b][4 + uu]  + b_ih[1024 + u] + b_hh[1024 + u];
        float gg = sg[0][b][8 + uu]  + sg[1][b][8 + uu]  + b_ih[2048 + u] + b_hh[2048 + u];
        float go = sg[0][b][12 + uu] + sg[1][b][12 + uu] + b_ih[3072 + u] + b_hh[3072 + u];
        int idx = b * 1024 + u;
        float c = sigmoid_fast(gf) * cx[idx] + sigmoid_fast(gi) * tanh_fast(gg);
        float h = sigmoid_fast(go) * tanh_fast(c);
        cx[idx] = c;
        hx[idx] = h;
        hx_all_t[idx] = h;
        ushort hh = f2bf_rne(h);
        nxh[idx] = hh;
        nxl[idx] = f2bf_rne(h - bf2f(hh));
    }
}

// ---------------------------------------------------------------------------
extern "C" void kernel_launch(void* const* d_in, const int* in_sizes, int n_in,
                              void* d_out, int out_size, void* d_ws, size_t ws_size,
                              hipStream_t stream) {
    const float* features = (const float*)d_in[0];
    const int*   captions = (const int*)d_in[1];
    const float* E      = (const float*)d_in[3];
    const float* W_feat = (const float*)d_in[4];
    const float* b_feat = (const float*)d_in[5];
    const float* W1     = (const float*)d_in[6];
    const float* b1     = (const float*)d_in[7];
    const float* W2     = (const float*)d_in[8];
    const float* b2     = (const float*)d_in[9];
    const float* V      = (const float*)d_in[10];
    // d_in[11] bV: softmax-invariant, unused
    const float* W_hi   = (const float*)d_in[12];
    const float* b_hi   = (const float*)d_in[13];
    const float* W_ci   = (const float*)d_in[14];
    const float* b_ci   = (const float*)d_in[15];
    const float* W_ih   = (const float*)d_in[16];
    const float* b_ih   = (const float*)d_in[17];
    const float* W_hh   = (const float*)d_in[18];
    const float* b_hh   = (const float*)d_in[19];
    const float* W_out  = (const float*)d_in[20];
    const float* b_out  = (const float*)d_in[21];
    float* out = (float*)d_out;

    // ---- workspace layout ----
    float* ws = (float*)d_ws;
    float* f_buf   = ws;                          // 6,422,528
    float* fa_buf  = f_buf + 6422528;             // 6,422,528
    float* fmean   = fa_buf + 6422528;            // 32,768
    float* hx      = fmean + 32768;               // 65,536
    float* cx      = hx + 65536;                  // 65,536
    float* hx_all  = cx + 65536;                  // 1,310,720
    float* ha      = hx_all + 1310720;            // 32,768
    ushort* p = (ushort*)(ha + 32768);
    ushort* wfeat_hi = p;            p += 1048576;
    ushort* wfeat_lo = p;            p += 1048576;
    ushort* w1_hi    = p;            p += 262144;
    ushort* w1_lo    = p;            p += 262144;
    ushort* wih_hi   = p;            p += 4194304;
    ushort* wih_lo   = p;            p += 4194304;
    ushort* whh_hi   = p;            p += 4194304;
    ushort* whh_lo   = p;            p += 4194304;
    ushort* xs_hi    = p;            p += 622592;
    ushort* xs_lo    = p;            p += 622592;
    ushort* ctx_hi   = p;            p += 32768;
    ushort* ctx_lo   = p;            p += 32768;
    ushort* hxp      = p;            p += 262144;   // [2 bufs][hi|lo][65536]
    // W_out planes reuse f_buf+fa_buf region after the step loop (41MB <= 51MB)
    ushort* wout_hi = (ushort*)f_buf;
    ushort* wout_lo = wout_hi + 10240000;

    // ---- precompute ----
    k_split<<<1048576 / 4 / 256, 256, 0, stream>>>(W_feat, wfeat_hi, wfeat_lo, 1048576);
    k_split<<<262144 / 4 / 256, 256, 0, stream>>>(W1, w1_hi, w1_lo, 262144);
    k_split<<<4194304 / 4 / 256, 256, 0, stream>>>(W_ih, wih_hi, wih_lo, 4194304);
    k_split<<<4194304 / 4 / 256, 256, 0, stream>>>(W_hh, whh_hi, whh_lo, 4194304);
    // f = features @ W_feat^T + b_feat  [12544,512], K=2048
    mfma_g<true><<<784, 256, 0, stream>>>(
        features, wfeat_hi, wfeat_lo, b_feat, f_buf, 512, 2048, 512, 4, 196);
    // fa = f @ W1^T + b1  [12544,512], K=512
    mfma_g<true><<<784, 256, 0, stream>>>(
        f_buf, w1_hi, w1_lo, b1, fa_buf, 512, 512, 512, 4, 196);
    k_fmean<<<BB, 256, 0, stream>>>(f_buf, fmean);
    k_init<<<BB, 256, 0, stream>>>(fmean, W_hi, b_hi, W_ci, b_ci, hx, cx);
    k_split<<<65536 / 4 / 256, 256, 0, stream>>>(hx, hxp, hxp + 65536, 65536);
    k_embed_split<<<STEPS * BB, 128, 0, stream>>>(captions, E, xs_hi, xs_lo);

    // ---- recurrent steps: 3 dispatches per step ----
    for (int t = 0; t < STEPS; ++t) {
        ushort* hx_rd = hxp + (size_t)(t & 1) * 131072;
        ushort* hx_wr = hxp + (size_t)((t + 1) & 1) * 131072;
        k_ha<<<256, 256, 0, stream>>>(hx, W2, b2, ha);
        k_att<<<BB, 1024, 0, stream>>>(f_buf, fa_buf, ha, V, ctx_hi, ctx_lo);
        k_gates_lstm<<<256, 512, 0, stream>>>(
            xs_hi + (size_t)t * BB * EMB, xs_lo + (size_t)t * BB * EMB,
            ctx_hi, ctx_lo, hx_rd, hx_rd + 65536,
            wih_hi, wih_lo, whh_hi, whh_lo, b_ih, b_hh,
            hx, cx, hx_wr, hx_wr + 65536,
            hx_all + (size_t)t * BB * HID);
    }

    // ---- vocab projection over all steps: [1216,10000], K=1024 ----
    k_split<<<10240000 / 4 / 256, 256, 0, stream>>>(W_out, wout_hi, wout_lo, 10240000);
    mfma_g<false><<<1501, 256, 0, stream>>>(
        hx_all, wout_hi, wout_lo, b_out, out, VOCAB, HID, VOCAB, 79, 19);
}

// Round 10
// 1697.744 us; speedup vs baseline: 4.7968x; 1.0589x over previous
//
#include <hip/hip_runtime.h>
#include <hip/hip_bf16.h>
#include <math.h>

#define BB 64
#define HW 196
#define FEAT 2048
#define EMB 512
#define HID 1024
#define ATT 512
#define VOCAB 10000
#define TT 20
#define STEPS 19

using bfrag = __attribute__((ext_vector_type(8))) short;   // 8 bf16 = 4 VGPR
using f32x4 = __attribute__((ext_vector_type(4))) float;

__device__ __forceinline__ float sigmoid_fast(float x) { return 1.0f / (1.0f + __expf(-x)); }
__device__ __forceinline__ float tanh_fast(float x) {
    float e = __expf(2.0f * x);
    return 1.0f - 2.0f / (e + 1.0f);
}
__device__ __forceinline__ ushort f2bf_rne(float f) {
    unsigned u = __float_as_uint(f);
    unsigned r = (u + 0x7FFFu + ((u >> 16) & 1u)) >> 16;
    return (ushort)r;
}
__device__ __forceinline__ float bf2f(ushort h) {
    return __uint_as_float(((unsigned)h) << 16);
}
// XOR bank swizzle for 16B LDS chunks. slot(lane window of 8) must be a
// permutation of 0..7: chunk = row*4 + (g ^ ((row>>1)&3)) gives slot
// (row&1)*4 + ((row>>1)&3) = row&7 on fragment reads (row = ..+l15, g fixed)
// AND on staging writes (r_=tid>>2, g_=tid&3). Conflict-free both sides.
__device__ __forceinline__ int sw_idx(int row, int g) { return row * 4 + (g ^ ((row >> 1) & 3)); }

// ---------------------------------------------------------------------------
// fp32 -> split bf16 planes: x = hi + lo.  n % 1024 == 0.
// ---------------------------------------------------------------------------
__global__ __launch_bounds__(256) void k_split(const float* __restrict__ x,
                                               ushort* __restrict__ hi,
                                               ushort* __restrict__ lo, int n)
{
    int i4 = (blockIdx.x * 256 + threadIdx.x) * 4;
    if (i4 >= n) return;
    float4 v = *(const float4*)(x + i4);
    float av[4] = {v.x, v.y, v.z, v.w};
    #pragma unroll
    for (int j = 0; j < 4; ++j) {
        ushort h = f2bf_rne(av[j]);
        hi[i4 + j] = h;
        lo[i4 + j] = f2bf_rne(av[j] - bf2f(h));
    }
}

// ---------------------------------------------------------------------------
// mfma_g: split-bf16 NT GEMM, 64(M) x 128(N) tile, BK=32, 4 waves
// (2 m-halves x 2 n-halves). 3-term: Ah*Bh + Ah*Bl + Al*Bh.
// A fp32 (split during staging); B pre-split planes with leading dim Bld
// (can exceed K for column-slice GEMMs). LDS XOR-swizzled (sw_idx).
// NFAST: consecutive swizzled blocks share the m-panel; else n-panel.
// T1 bijective XCD-chunk swizzle. M multiple of 64; N ragged OK.
// ---------------------------------------------------------------------------
template<bool NFAST>
__global__ __launch_bounds__(256) void mfma_g(
    const float* __restrict__ A,
    const ushort* __restrict__ Bhi, const ushort* __restrict__ Blo,
    const float* __restrict__ bias, float* __restrict__ C,
    int N, int K, int Bld, int ldc, int NXB, int NMB)
{
    __shared__ __align__(16) ushort sAh[256 * 8];
    __shared__ __align__(16) ushort sAl[256 * 8];
    __shared__ __align__(16) ushort sBh[512 * 8];
    __shared__ __align__(16) ushort sBl[512 * 8];

    const int tid = threadIdx.x;

    // XCD-chunked bijective swizzle
    const int nwg = NXB * NMB;
    const int q = nwg >> 3, r = nwg & 7;
    const int xcd = blockIdx.x & 7, sidx = blockIdx.x >> 3;
    const int wg = (xcd < r) ? (xcd * (q + 1) + sidx)
                             : (r * (q + 1) + (xcd - r) * q + sidx);
    int im, inb;
    if (NFAST) { inb = wg % NXB; im = wg / NXB; }
    else       { im = wg % NMB; inb = wg / NMB; }
    const int m0 = im * 64;
    const int n0 = inb * 128;

    const int lane = tid & 63;
    const int w = tid >> 6;
    const int mh = (w & 1) * 32;
    const int nh = (w >> 1) * 64;
    const int g = lane >> 4, l15 = lane & 15;

    f32x4 acc[2][4] = {};

    for (int k0 = 0; k0 < K; k0 += 32) {
        __syncthreads();
        {   // A: fp32 -> hi/lo, swizzled store
            int r_ = tid >> 2, g_ = tid & 3;
            const float* ap = A + (size_t)(m0 + r_) * K + k0 + g_ * 8;
            float av[8];
            *(float4*)(av)     = *(const float4*)(ap);
            *(float4*)(av + 4) = *(const float4*)(ap + 4);
            bfrag vh, vl;
            #pragma unroll
            for (int j = 0; j < 8; ++j) {
                ushort h = f2bf_rne(av[j]);
                vh[j] = (short)h;
                vl[j] = (short)f2bf_rne(av[j] - bf2f(h));
            }
            int c = sw_idx(r_, g_) * 8;
            *(bfrag*)&sAh[c] = vh;
            *(bfrag*)&sAl[c] = vl;
        }
        #pragma unroll
        for (int i = 0; i < 4; ++i) {   // B planes, swizzled store
            int c = tid + i * 256;
            int pl = c >> 9, idx2 = c & 511;
            int r_ = idx2 >> 2, g_ = idx2 & 3;
            int brow = min(n0 + r_, N - 1);
            const ushort* src = (pl ? Blo : Bhi) + (size_t)brow * Bld + k0 + g_ * 8;
            int cc = sw_idx(r_, g_) * 8;
            if (pl) *(bfrag*)&sBl[cc] = *(const bfrag*)src;
            else    *(bfrag*)&sBh[cc] = *(const bfrag*)src;
        }
        __syncthreads();

        bfrag ah[2], al[2], bh[4], bl[4];
        #pragma unroll
        for (int s = 0; s < 2; ++s) {
            int c = sw_idx(mh + s * 16 + l15, g) * 8;
            ah[s] = *(const bfrag*)&sAh[c];
            al[s] = *(const bfrag*)&sAl[c];
        }
        #pragma unroll
        for (int u = 0; u < 4; ++u) {
            int c = sw_idx(nh + u * 16 + l15, g) * 8;
            bh[u] = *(const bfrag*)&sBh[c];
            bl[u] = *(const bfrag*)&sBl[c];
        }
        #pragma unroll
        for (int s = 0; s < 2; ++s)
            #pragma unroll
            for (int u = 0; u < 4; ++u) {
                acc[s][u] = __builtin_amdgcn_mfma_f32_16x16x32_bf16(ah[s], bh[u], acc[s][u], 0, 0, 0);
                acc[s][u] = __builtin_amdgcn_mfma_f32_16x16x32_bf16(ah[s], bl[u], acc[s][u], 0, 0, 0);
                acc[s][u] = __builtin_amdgcn_mfma_f32_16x16x32_bf16(al[s], bh[u], acc[s][u], 0, 0, 0);
            }
    }

    #pragma unroll
    for (int s = 0; s < 2; ++s)
        #pragma unroll
        for (int u = 0; u < 4; ++u) {
            int col = n0 + nh + u * 16 + l15;
            if (col < N) {
                float bv = bias ? bias[col] : 0.f;
                #pragma unroll
                for (int rr = 0; rr < 4; ++rr) {
                    int row = m0 + mh + s * 16 + g * 4 + rr;
                    C[(size_t)row * ldc + col] = acc[s][u][rr] + bv;
                }
            }
        }
}

// ---------------------------------------------------------------------------
__global__ __launch_bounds__(256) void k_fmean(const float* __restrict__ f,
                                               float* __restrict__ fmean)
{
    int b = blockIdx.x, tid = threadIdx.x;
    for (int e = tid; e < EMB; e += 256) {
        const float* fb = f + (size_t)b * HW * EMB + e;
        float s = 0.f;
        for (int h = 0; h < HW; ++h) s += fb[(size_t)h * EMB];
        fmean[b * EMB + e] = s * (1.0f / HW);
    }
}

__global__ __launch_bounds__(256) void k_init(
    const float* __restrict__ fmean,
    const float* __restrict__ W_hi, const float* __restrict__ b_hi,
    const float* __restrict__ W_ci, const float* __restrict__ b_ci,
    float* __restrict__ hx, float* __restrict__ cx)
{
    int b = blockIdx.x, tid = threadIdx.x;
    __shared__ float fm[EMB];
    for (int i = tid; i < EMB; i += 256) fm[i] = fmean[b * EMB + i];
    __syncthreads();
    for (int u = tid; u < HID; u += 256) {
        const float4* w1 = (const float4*)(W_hi + (size_t)u * EMB);
        const float4* w2 = (const float4*)(W_ci + (size_t)u * EMB);
        float a1 = b_hi[u], a2 = b_ci[u];
        for (int k = 0; k < EMB / 4; ++k) {
            float4 y1 = w1[k], y2 = w2[k];
            float x0 = fm[4*k], x1 = fm[4*k+1], x2 = fm[4*k+2], x3 = fm[4*k+3];
            a1 += x0*y1.x + x1*y1.y + x2*y1.z + x3*y1.w;
            a2 += x0*y2.x + x1*y2.y + x2*y2.z + x3*y2.w;
        }
        hx[b * HID + u] = a1;
        cx[b * HID + u] = a2;
    }
}

// xs_f[t*64+b][:] = E[captions[b][t]][:]  (fp32; feeds the hoisted GEMM)
__global__ __launch_bounds__(128) void k_embed(const int* __restrict__ cap,
                                               const float* __restrict__ E,
                                               float* __restrict__ xs_f)
{
    int blk = blockIdx.x;
    int t = blk / BB, b = blk % BB;
    int c = cap[b * TT + t];
    const float4* src = (const float4*)(E + (size_t)c * EMB);
    float4* dst = (float4*)(xs_f + ((size_t)t * BB + b) * EMB);
    dst[threadIdx.x] = src[threadIdx.x];
}

// ---------------------------------------------------------------------------
// k_ha: ha[b][a] = hx[b].W2[a] + b2[a].  grid 256: block -> 16 a's x 8 b's.
// ---------------------------------------------------------------------------
__global__ __launch_bounds__(256) void k_ha(
    const float* __restrict__ hx, const float* __restrict__ W2,
    const float* __restrict__ b2, float* __restrict__ ha)
{
    __shared__ __align__(16) float hx_s[8][1028];
    __shared__ float part[256];
    const int tid = threadIdx.x;
    const int a0 = (blockIdx.x >> 3) * 16;
    const int b0 = (blockIdx.x & 7) * 8;

    for (int i = tid; i < 8 * 256; i += 256) {
        int r = i >> 8, c4 = i & 255;
        *(float4*)&hx_s[r][c4 * 4] = *(const float4*)(hx + (size_t)(b0 + r) * HID + c4 * 4);
    }
    __syncthreads();

    const int a_i = tid >> 4;
    const int b_i = (tid >> 1) & 7;
    const int half = tid & 1;
    const float4* wr = (const float4*)(W2 + (size_t)(a0 + a_i) * HID + half * 512);
    const float* xr = &hx_s[b_i][half * 512];
    float s = 0.f;
    #pragma unroll 8
    for (int i = 0; i < 128; ++i) {
        float4 w = wr[i];
        float4 x = *(const float4*)(xr + i * 4);
        s += w.x*x.x + w.y*x.y + w.z*x.z + w.w*x.w;
    }
    part[tid] = s;
    __syncthreads();
    if (!half)
        ha[(size_t)(b0 + b_i) * ATT + a0 + a_i] = part[tid] + part[tid + 1] + b2[a0 + a_i];
}

// ---------------------------------------------------------------------------
// k_att: one block per b (64 x 1024): logits -> softmax -> ctx -> planes.
// ---------------------------------------------------------------------------
__global__ __launch_bounds__(1024) void k_att(
    const float* __restrict__ f, const float* __restrict__ fa,
    const float* __restrict__ ha, const float* __restrict__ V,
    ushort* __restrict__ ctx_hi, ushort* __restrict__ ctx_lo)
{
    __shared__ __align__(16) float smem[2048];
    const int b = blockIdx.x;
    const int tid = threadIdx.x;
    const int lane = tid & 63;
    const int wid = tid >> 6;

    float* ha_s = smem;          // 512
    float* V_s  = smem + 512;    // 512
    float* w_s  = smem + 1024;   // 256 (196 used)
    float* red  = smem + 1280;   // 256
    float* pc   = smem + 1536;   // 512

    if (tid < ATT) { ha_s[tid] = ha[b * ATT + tid]; V_s[tid] = V[tid]; }
    __syncthreads();

    for (int h = wid; h < HW; h += 16) {
        const float4* fr = (const float4*)(fa + ((size_t)b * HW + h) * ATT);
        float s = 0.f;
        #pragma unroll
        for (int q = 0; q < 2; ++q) {
            int i4 = q * 64 + lane;
            float4 fv = fr[i4];
            float4 hv = *(const float4*)&ha_s[i4 * 4];
            float4 vv = *(const float4*)&V_s[i4 * 4];
            s += tanh_fast(fv.x + hv.x) * vv.x + tanh_fast(fv.y + hv.y) * vv.y
               + tanh_fast(fv.z + hv.z) * vv.z + tanh_fast(fv.w + hv.w) * vv.w;
        }
        #pragma unroll
        for (int off = 32; off > 0; off >>= 1) s += __shfl_down(s, off);
        if (lane == 0) w_s[h] = s;
    }
    __syncthreads();

    float v = (tid < HW) ? w_s[tid] : -INFINITY;
    if (tid < 256) red[tid] = v;
    __syncthreads();
    for (int s2 = 128; s2 > 0; s2 >>= 1) {
        if (tid < s2) red[tid] = fmaxf(red[tid], red[tid + s2]);
        __syncthreads();
    }
    float mx = red[0];
    __syncthreads();
    float e = (tid < HW) ? __expf(v - mx) : 0.f;
    if (tid < 256) red[tid] = e;
    __syncthreads();
    for (int s2 = 128; s2 > 0; s2 >>= 1) {
        if (tid < s2) red[tid] += red[tid + s2];
        __syncthreads();
    }
    float inv = 1.0f / red[0];
    if (tid < HW) w_s[tid] = e * inv;
    __syncthreads();

    {
        int e0 = tid & 511, grp = tid >> 9;
        const float* fb = f + (size_t)b * HW * EMB + e0;
        float s = 0.f;
        int h0 = grp * 98;
        for (int h = h0; h < h0 + 98; ++h)
            s = fmaf(w_s[h], fb[(size_t)h * EMB], s);
        if (grp) pc[e0] = s;
        __syncthreads();
        if (!grp) {
            float c = s + pc[e0];
            ushort ch = f2bf_rne(c);
            ctx_hi[b * EMB + e0] = ch;
            ctx_lo[b * EMB + e0] = f2bf_rne(c - bf2f(ch));
        }
    }
}

// ---------------------------------------------------------------------------
// k_gates_lstm: recurrent half of the gates GEMM (K=1536: ctx 512 + hx 1024;
// the xs.W_ih[:, :512] term is precomputed in gxs) + fused LSTM.
// grid 256 x 512 thr (8 waves). Wave (mt, kh): kh0 = ctx + hx[0:256) (24 kk),
// kh1 = hx[256:1024) (24 kk) -- balanced. ncol(l15) = (l15>>2)*1024 + bk*4 +
// (l15&3). Epilogue: 8KB LDS reduce + gxs + biases -> LSTM -> hx, cx,
// next hx planes (parity double-buffered), hx_all fp32.
// ---------------------------------------------------------------------------
__global__ __launch_bounds__(512) void k_gates_lstm(
    const float* __restrict__ gxs_t,                                  // [64][4096]
    const ushort* __restrict__ cth, const ushort* __restrict__ ctl,   // [64][512]
    const ushort* __restrict__ hxh, const ushort* __restrict__ hxl,   // [64][1024] read
    const ushort* __restrict__ wihh, const ushort* __restrict__ wihl, // [4096][1024]
    const ushort* __restrict__ whhh, const ushort* __restrict__ whhl, // [4096][1024]
    const float* __restrict__ b_ih, const float* __restrict__ b_hh,
    float* __restrict__ hx, float* __restrict__ cx,
    ushort* __restrict__ nxh, ushort* __restrict__ nxl,               // write planes
    float* __restrict__ hx_all_t)
{
    __shared__ float sg[2][64][16];   // 8 KB
    const int tid = threadIdx.x, bk = blockIdx.x;
    const int lane = tid & 63, wid = tid >> 6;
    const int mt = wid & 3, kh = wid >> 2;
    const int l15 = lane & 15, g = lane >> 4;
    const int arow = mt * 16 + l15;
    const int ncol = (l15 >> 2) * 1024 + bk * 4 + (l15 & 3);
    const int koff = g * 8;

    f32x4 acc0 = {}, acc1 = {};

    if (kh == 0) {
        {   // ctx . W_ih[:, 512:1024)  (16 kk)
            const ushort* ah = cth + (size_t)arow * 512 + koff;
            const ushort* al = ctl + (size_t)arow * 512 + koff;
            const ushort* bh = wihh + (size_t)ncol * 1024 + 512 + koff;
            const ushort* bl = wihl + (size_t)ncol * 1024 + 512 + koff;
            #pragma unroll 4
            for (int kk = 0; kk < 16; ++kk) {
                bfrag a_h = *(const bfrag*)(ah + kk * 32);
                bfrag a_l = *(const bfrag*)(al + kk * 32);
                bfrag b_h = *(const bfrag*)(bh + kk * 32);
                bfrag b_l = *(const bfrag*)(bl + kk * 32);
                acc0 = __builtin_amdgcn_mfma_f32_16x16x32_bf16(a_h, b_h, acc0, 0, 0, 0);
                acc1 = __builtin_amdgcn_mfma_f32_16x16x32_bf16(a_h, b_l, acc1, 0, 0, 0);
                acc1 = __builtin_amdgcn_mfma_f32_16x16x32_bf16(a_l, b_h, acc1, 0, 0, 0);
            }
        }
        {   // hx[0:256) . W_hh[:, 0:256)  (8 kk)
            const ushort* ah = hxh + (size_t)arow * 1024 + koff;
            const ushort* al = hxl + (size_t)arow * 1024 + koff;
            const ushort* bh = whhh + (size_t)ncol * 1024 + koff;
            const ushort* bl = whhl + (size_t)ncol * 1024 + koff;
            #pragma unroll 4
            for (int kk = 0; kk < 8; ++kk) {
                bfrag a_h = *(const bfrag*)(ah + kk * 32);
                bfrag a_l = *(const bfrag*)(al + kk * 32);
                bfrag b_h = *(const bfrag*)(bh + kk * 32);
                bfrag b_l = *(const bfrag*)(bl + kk * 32);
                acc0 = __builtin_amdgcn_mfma_f32_16x16x32_bf16(a_h, b_h, acc0, 0, 0, 0);
                acc1 = __builtin_amdgcn_mfma_f32_16x16x32_bf16(a_h, b_l, acc1, 0, 0, 0);
                acc1 = __builtin_amdgcn_mfma_f32_16x16x32_bf16(a_l, b_h, acc1, 0, 0, 0);
            }
        }
    } else {
        // hx[256:1024) . W_hh[:, 256:1024)  (24 kk)
        const ushort* ah = hxh + (size_t)arow * 1024 + 256 + koff;
        const ushort* al = hxl + (size_t)arow * 1024 + 256 + koff;
        const ushort* bh = whhh + (size_t)ncol * 1024 + 256 + koff;
        const ushort* bl = whhl + (size_t)ncol * 1024 + 256 + koff;
        #pragma unroll 4
        for (int kk = 0; kk < 24; ++kk) {
            bfrag a_h = *(const bfrag*)(ah + kk * 32);
            bfrag a_l = *(const bfrag*)(al + kk * 32);
            bfrag b_h = *(const bfrag*)(bh + kk * 32);
            bfrag b_l = *(const bfrag*)(bl + kk * 32);
            acc0 = __builtin_amdgcn_mfma_f32_16x16x32_bf16(a_h, b_h, acc0, 0, 0, 0);
            acc1 = __builtin_amdgcn_mfma_f32_16x16x32_bf16(a_h, b_l, acc1, 0, 0, 0);
            acc1 = __builtin_amdgcn_mfma_f32_16x16x32_bf16(a_l, b_h, acc1, 0, 0, 0);
        }
    }

    #pragma unroll
    for (int rr = 0; rr < 4; ++rr)
        sg[kh][mt * 16 + g * 4 + rr][l15] = acc0[rr] + acc1[rr];
    __syncthreads();

    if (tid < 256) {
        int b = tid >> 2, uu = tid & 3;
        int u = bk * 4 + uu;
        const float* gx = gxs_t + (size_t)b * 4096;
        float gi = sg[0][b][uu]      + sg[1][b][uu]      + gx[u]        + b_ih[u]        + b_hh[u];
        float gf = sg[0][b][4 + uu]  + sg[1][b][4 + uu]  + gx[1024 + u] + b_ih[1024 + u] + b_hh[1024 + u];
        float gg = sg[0][b][8 + uu]  + sg[1][b][8 + uu]  + gx[2048 + u] + b_ih[2048 + u] + b_hh[2048 + u];
        float go = sg[0][b][12 + uu] + sg[1][b][12 + uu] + gx[3072 + u] + b_ih[3072 + u] + b_hh[3072 + u];
        int idx = b * 1024 + u;
        float c = sigmoid_fast(gf) * cx[idx] + sigmoid_fast(gi) * tanh_fast(gg);
        float h = sigmoid_fast(go) * tanh_fast(c);
        cx[idx] = c;
        hx[idx] = h;
        hx_all_t[idx] = h;
        ushort hh = f2bf_rne(h);
        nxh[idx] = hh;
        nxl[idx] = f2bf_rne(h - bf2f(hh));
    }
}

// ---------------------------------------------------------------------------
extern "C" void kernel_launch(void* const* d_in, const int* in_sizes, int n_in,
                              void* d_out, int out_size, void* d_ws, size_t ws_size,
                              hipStream_t stream) {
    const float* features = (const float*)d_in[0];
    const int*   captions = (const int*)d_in[1];
    const float* E      = (const float*)d_in[3];
    const float* W_feat = (const float*)d_in[4];
    const float* b_feat = (const float*)d_in[5];
    const float* W1     = (const float*)d_in[6];
    const float* b1     = (const float*)d_in[7];
    const float* W2     = (const float*)d_in[8];
    const float* b2     = (const float*)d_in[9];
    const float* V      = (const float*)d_in[10];
    // d_in[11] bV: softmax-invariant, unused
    const float* W_hi   = (const float*)d_in[12];
    const float* b_hi   = (const float*)d_in[13];
    const float* W_ci   = (const float*)d_in[14];
    const float* b_ci   = (const float*)d_in[15];
    const float* W_ih   = (const float*)d_in[16];
    const float* b_ih   = (const float*)d_in[17];
    const float* W_hh   = (const float*)d_in[18];
    const float* b_hh   = (const float*)d_in[19];
    const float* W_out  = (const float*)d_in[20];
    const float* b_out  = (const float*)d_in[21];
    float* out = (float*)d_out;

    // ---- workspace layout ----
    float* ws = (float*)d_ws;
    float* f_buf   = ws;                          // 6,422,528
    float* fa_buf  = f_buf + 6422528;             // 6,422,528
    float* fmean   = fa_buf + 6422528;            // 32,768
    float* hx      = fmean + 32768;               // 65,536
    float* cx      = hx + 65536;                  // 65,536
    float* hx_all  = cx + 65536;                  // 1,310,720
    float* ha      = hx_all + 1310720;            // 32,768
    float* xs_f    = ha + 32768;                  // 622,592
    float* gxs     = xs_f + 622592;               // 1216*4096 = 4,980,736
    ushort* p = (ushort*)(gxs + 4980736);
    ushort* wfeat_hi = p;            p += 1048576;
    ushort* wfeat_lo = p;            p += 1048576;
    ushort* w1_hi    = p;            p += 262144;
    ushort* w1_lo    = p;            p += 262144;
    ushort* wih_hi   = p;            p += 4194304;
    ushort* wih_lo   = p;            p += 4194304;
    ushort* whh_hi   = p;            p += 4194304;
    ushort* whh_lo   = p;            p += 4194304;
    ushort* ctx_hi   = p;            p += 32768;
    ushort* ctx_lo   = p;            p += 32768;
    ushort* hxp      = p;            p += 262144;   // [2 bufs][hi|lo][65536]
    // W_out planes reuse f_buf+fa_buf region after the step loop (41MB <= 51MB)
    ushort* wout_hi = (ushort*)f_buf;
    ushort* wout_lo = wout_hi + 10240000;

    // ---- precompute ----
    k_split<<<1048576 / 4 / 256, 256, 0, stream>>>(W_feat, wfeat_hi, wfeat_lo, 1048576);
    k_split<<<262144 / 4 / 256, 256, 0, stream>>>(W1, w1_hi, w1_lo, 262144);
    k_split<<<4194304 / 4 / 256, 256, 0, stream>>>(W_ih, wih_hi, wih_lo, 4194304);
    k_split<<<4194304 / 4 / 256, 256, 0, stream>>>(W_hh, whh_hi, whh_lo, 4194304);
    k_embed<<<STEPS * BB, 128, 0, stream>>>(captions, E, xs_f);
    // f = features @ W_feat^T + b_feat  [12544,512], K=2048
    mfma_g<true><<<784, 256, 0, stream>>>(
        features, wfeat_hi, wfeat_lo, b_feat, f_buf, 512, 2048, 2048, 512, 4, 196);
    // fa = f @ W1^T + b1  [12544,512], K=512
    mfma_g<true><<<784, 256, 0, stream>>>(
        f_buf, w1_hi, w1_lo, b1, fa_buf, 512, 512, 512, 512, 4, 196);
    // gxs = xs_flat @ W_ih[:, 0:512]^T  [1216,4096], K=512, Bld=1024, no bias
    mfma_g<false><<<608, 256, 0, stream>>>(
        xs_f, wih_hi, wih_lo, nullptr, gxs, 4096, 512, 1024, 4096, 32, 19);
    k_fmean<<<BB, 256, 0, stream>>>(f_buf, fmean);
    k_init<<<BB, 256, 0, stream>>>(fmean, W_hi, b_hi, W_ci, b_ci, hx, cx);
    k_split<<<65536 / 4 / 256, 256, 0, stream>>>(hx, hxp, hxp + 65536, 65536);

    // ---- recurrent steps: 3 dispatches per step ----
    for (int t = 0; t < STEPS; ++t) {
        ushort* hx_rd = hxp + (size_t)(t & 1) * 131072;
        ushort* hx_wr = hxp + (size_t)((t + 1) & 1) * 131072;
        k_ha<<<256, 256, 0, stream>>>(hx, W2, b2, ha);
        k_att<<<BB, 1024, 0, stream>>>(f_buf, fa_buf, ha, V, ctx_hi, ctx_lo);
        k_gates_lstm<<<256, 512, 0, stream>>>(
            gxs + (size_t)t * BB * 4096,
            ctx_hi, ctx_lo, hx_rd, hx_rd + 65536,
            wih_hi, wih_lo, whh_hi, whh_lo, b_ih, b_hh,
            hx, cx, hx_wr, hx_wr + 65536,
            hx_all + (size_t)t * BB * HID);
    }

    // ---- vocab projection over all steps: [1216,10000], K=1024 ----
    k_split<<<10240000 / 4 / 256, 256, 0, stream>>>(W_out, wout_hi, wout_lo, 10240000);
    mfma_g<false><<<1501, 256, 0, stream>>>(
        hx_all, wout_hi, wout_lo, b_out, out, VOCAB, HID, 1024, VOCAB, 79, 19);
}